// Round 17
// baseline (1572.879 us; speedup 1.0000x reference)
//
#include <hip/hip_runtime.h>
#include <hip/hip_bf16.h>
#include <math.h>

// ---------------------------------------------------------------------------
// Problem constants
// ---------------------------------------------------------------------------
#define BB   128     // batch
#define TT   1024    // time
#define CC_  512     // channels / variates (N)
#define DD   1024    // model dim
#define DF_  2048    // fc hidden
#define HH   64      // pool hidden
#define INV_SQRT_D 0.03125f   // 1/sqrt(1024)

typedef _Float16 f16;
typedef __attribute__((ext_vector_type(8))) _Float16 f16x8;
typedef __attribute__((ext_vector_type(4))) _Float16 f16x4;
typedef __attribute__((ext_vector_type(2))) _Float16 f16x2;
typedef __attribute__((ext_vector_type(4))) float f32x4;

__device__ __forceinline__ void gload_lds16(const void* g, void* l) {
    // async global->LDS, 16B per lane; LDS dest = wave-uniform base + lane*16
    __builtin_amdgcn_global_load_lds(
        (const __attribute__((address_space(1))) void*)g,
        (__attribute__((address_space(3))) void*)l, 16, 0, 0);
}

// Tile-packed operand layout (half-element index).  For a GEMM operand with
// row dim r (tiles of 128) and contraction dim k (tiles of 32, sub-chunks
// of 8): element (r,k) lives at
//   ((r>>7)*(K>>5) + (k>>5))*4096 + ((k>>3)&3)*1024 + (r&127)*8 + (k&7)
__device__ __forceinline__ long long paddr(long long r, int k, int K) {
    return ((r >> 7) * (long long)(K >> 5) + (k >> 5)) * 4096LL
         + (long long)(((k >> 3) & 3) * 1024 + ((int)(r & 127)) * 8 + (k & 7));
}

// ---------------------------------------------------------------------------
// fp16 MFMA GEMM (fp32 accumulate), 128x128 tile, BK=64, 4 waves,
// single-buffered 2-barrier loop, PACKED operands.
//   C[m,n] = act(alpha*sum_k A[m,k]*B[n,k] + add_c + bias[n])
//   OUT: 0 = fp32 C[M][N] row-major;  1 = packed f16 (r=m, k=n, K=N);
//        2 = packed f16 transposed (r=n, k=m, K=M)
//   ACT: 0 = none, 2 = exact gelu
// M,N multiples of 128; K multiple of 64.
// ---------------------------------------------------------------------------
template <int OUT, int ACT = 0>
__global__ __launch_bounds__(256, 4) void mfma_gemm(
    const f16* __restrict__ A, const f16* __restrict__ B,
    const float* __restrict__ bias, const float* __restrict__ add_c,
    void* __restrict__ C0,
    int M, int N, int K,
    long long sA, long long sB, long long sC, float alpha)
{
    // ---- XCD swizzle on flattened (x,y); identity when nwg % 8 != 0 ----
    const int gx = gridDim.x;
    const int nwg = gx * gridDim.y;
    int lin = blockIdx.y * gx + blockIdx.x;
    if ((nwg & 7) == 0) {
        const int cpx = nwg >> 3;
        lin = (lin & 7) * cpx + (lin >> 3);
    }
    const int bx = lin % gx, by = lin / gx;

    const int bz   = blockIdx.z;
    const int t    = threadIdx.x;
    const int wave = t >> 6, lane = t & 63;
    const int m0 = by * 128, n0 = bx * 128;
    const int wm = (wave >> 1) * 64, wn = (wave & 1) * 64;

    __shared__ __align__(16) f16 As[2][4096];   // 8 KB per sub-tile
    __shared__ __align__(16) f16 Bs[2][4096];

    f32x4 acc[4][4] = {};

    const int wbyte = wave * 1024;               // wave-uniform LDS base
    const long long tA = (long long)bz * sA + (long long)(m0 >> 7) * (K >> 5) * 4096;
    const long long tB = (long long)bz * sB + (long long)(n0 >> 7) * (K >> 5) * 4096;
    const f16* pA = A + tA + t * 8;
    const f16* pB = B + tB + t * 8;

    const int q   = lane >> 4;   // k-chunk for fragment reads
    const int r16 = lane & 15;

    for (int k0 = 0; k0 < K; k0 += 64) {
        const long long ko = (long long)(k0 >> 5) * 4096;
        __syncthreads();                       // previous compute done
        gload_lds16(pA + ko,        (char*)(&As[0][0]) + wbyte);
        gload_lds16(pA + ko + 2048, (char*)(&As[0][0]) + wbyte + 4096);
        gload_lds16(pA + ko + 4096, (char*)(&As[1][0]) + wbyte);
        gload_lds16(pA + ko + 6144, (char*)(&As[1][0]) + wbyte + 4096);
        gload_lds16(pB + ko,        (char*)(&Bs[0][0]) + wbyte);
        gload_lds16(pB + ko + 2048, (char*)(&Bs[0][0]) + wbyte + 4096);
        gload_lds16(pB + ko + 4096, (char*)(&Bs[1][0]) + wbyte);
        gload_lds16(pB + ko + 6144, (char*)(&Bs[1][0]) + wbyte + 4096);
        __syncthreads();                       // drains vmcnt: tiles ready

        #pragma unroll
        for (int s = 0; s < 2; ++s) {
            const f16x8* AV = (const f16x8*)(&As[s][0]);
            const f16x8* BV = (const f16x8*)(&Bs[s][0]);
            f16x8 bfr[4];
            #pragma unroll
            for (int j = 0; j < 4; ++j)
                bfr[j] = BV[q * 128 + wn + j * 16 + r16];
            __builtin_amdgcn_s_setprio(1);
            #pragma unroll
            for (int i = 0; i < 4; ++i) {
                const f16x8 a = AV[q * 128 + wm + i * 16 + r16];
                #pragma unroll
                for (int j = 0; j < 4; ++j)
                    acc[i][j] = __builtin_amdgcn_mfma_f32_16x16x32_f16(
                        a, bfr[j], acc[i][j], 0, 0, 0);
            }
            __builtin_amdgcn_s_setprio(0);
        }
    }

    // epilogue: C/D layout col = lane&15, row = (lane>>4)*4 + r
    const float cadd = add_c ? add_c[0] : 0.0f;
    const int col = lane & 15;
    const int rb  = (lane >> 4) * 4;
    #pragma unroll
    for (int j = 0; j < 4; ++j) {
        const int n = n0 + wn + j * 16 + col;
        const float bv = bias ? bias[n] : 0.0f;
        #pragma unroll
        for (int i = 0; i < 4; ++i) {
            const int m = m0 + wm + i * 16 + rb;
            f32x4 v = acc[i][j];
            #pragma unroll
            for (int r = 0; r < 4; ++r) {
                v[r] = v[r] * alpha + cadd + bv;
                if constexpr (ACT == 2)
                    v[r] = 0.5f * v[r] * (1.0f + erff(v[r] * 0.70710678118654752f));
            }
            if constexpr (OUT == 0) {
                float* C = (float*)C0 + (long long)bz * sC;
                #pragma unroll
                for (int r = 0; r < 4; ++r) C[(long long)(m + r) * N + n] = v[r];
            } else if constexpr (OUT == 1) {
                // packed: (r=m+r, k=n), K=N
                f16* C = (f16*)C0 + (long long)bz * sC;
                #pragma unroll
                for (int r = 0; r < 4; ++r)
                    C[paddr(m + r, n, N)] = (f16)v[r];
            } else {
                // packed transposed: (r=n, k=m..m+3), K=M;  m%8 in {0,4}
                f16* C = (f16*)C0 + (long long)bz * sC;
                f16 p[4];
                #pragma unroll
                for (int r = 0; r < 4; ++r) p[r] = (f16)v[r];
                *reinterpret_cast<f16x4*>(&C[paddr(n, m, M)]) =
                    *reinterpret_cast<f16x4*>(p);
            }
        }
    }
}

// ---------------------------------------------------------------------------
// fp32 [R][Cc] -> packed fp16 (rows = Cc-dim, k = original row dim, len R).
// Coalesced: write phase emits f16x8 per thread (contiguous in packed layout).
// tile[rr][cc] = in[(r0+rr)*Cc + (c0+cc)]; output (row c0+c, k r0+8q+j)
// value = tile[8q+j][c].
// ---------------------------------------------------------------------------
__global__ __launch_bounds__(256) void transpose_h_kernel(
    const float* __restrict__ in, f16* __restrict__ o,
    int R, int Cc, long long sIn, long long sOut)
{
    const int b = blockIdx.z;
    in += (long long)b * sIn; o += (long long)b * sOut;
    __shared__ float tile[32][33];
    const int c0 = blockIdx.x * 32, r0 = blockIdx.y * 32;
    const int tx = threadIdx.x & 31, ty = threadIdx.x >> 5;   // 32 x 8
    #pragma unroll
    for (int i = 0; i < 32; i += 8)
        tile[ty + i][tx] = in[(long long)(r0 + ty + i) * Cc + (c0 + tx)];
    __syncthreads();
    // write: thread t<128: c = t&31, q = t>>5; f16x8 of k = r0+8q+0..7
    if (threadIdx.x < 128) {
        const int c = threadIdx.x & 31, q = threadIdx.x >> 5;
        f16 p[8];
        #pragma unroll
        for (int j = 0; j < 8; ++j) p[j] = (f16)tile[8 * q + j][c];
        const long long base =
            (((long long)(c0 + c) >> 7) * (long long)(R >> 5) + (r0 >> 5)) * 4096LL
            + q * 1024 + ((c0 + c) & 127) * 8;
        *reinterpret_cast<f16x8*>(&o[base]) = *reinterpret_cast<f16x8*>(p);
    }
}

// fp32 [R][1024] -> packed fp16 (K=1024)
__global__ __launch_bounds__(256) void cvt_h_kernel(
    const float* __restrict__ in, f16* __restrict__ o, long long n)
{
    const long long i = ((long long)blockIdx.x * 256 + threadIdx.x) * 4;
    if (i >= n) return;
    const float4 v = *reinterpret_cast<const float4*>(in + i);
    f16 p[4] = {(f16)v.x, (f16)v.y, (f16)v.z, (f16)v.w};
    const long long r = i >> 10;
    const int k = (int)(i & 1023);
    *reinterpret_cast<f16x4*>(&o[paddr(r, k, 1024)]) = *reinterpret_cast<f16x4*>(p);
}

// zero-fill f16 buffer (n halves, multiple of 2048)
__global__ __launch_bounds__(256) void zero_h_kernel(f16* __restrict__ p, long long n)
{
    const long long i = ((long long)blockIdx.x * 256 + threadIdx.x) * 8;
    if (i >= n) return;
    f16x8 z = {};
    *reinterpret_cast<f16x8*>(p + i) = z;
}

// bias pad: out[0..63]=in, out[64..127]=0
__global__ __launch_bounds__(128) void pad_bias_kernel(
    const float* __restrict__ in, float* __restrict__ o)
{
    const int i = threadIdx.x;
    o[i] = (i < HH) ? in[i] : 0.0f;
}

// ---------------------------------------------------------------------------
// LayerNorm over K=1024 on PACKED f16, in place, COALESCED.
// One block = one 128-row group (32 tiles x 4096 halves = 256 KB contiguous).
// ---------------------------------------------------------------------------
__global__ __launch_bounds__(256) void layernorm_pg_kernel(
    f16* __restrict__ x, const float* __restrict__ g, const float* __restrict__ b)
{
    f16* base = x + (long long)blockIdx.x * 131072;   // 128 rows * 1024 k
    const int t = threadIdx.x;
    const int r = t & 127;
    const int h = t >> 7;

    __shared__ float gs[1024], bs[1024];
    __shared__ float ssum[256], ssq[256];
    for (int i = t; i < 1024; i += 256) { gs[i] = g[i]; bs[i] = b[i]; }

    // pass 1: per-(row,half) accumulate
    float sum = 0.0f, sq = 0.0f;
    for (int tile = 0; tile < 32; ++tile) {
        #pragma unroll
        for (int qq = 0; qq < 2; ++qq) {
            const f16x8 v = *reinterpret_cast<const f16x8*>(
                base + tile * 4096 + (h * 2 + qq) * 1024 + r * 8);
            #pragma unroll
            for (int j = 0; j < 8; ++j) {
                const float f = (float)v[j];
                sum += f; sq += f * f;
            }
        }
    }
    ssum[t] = sum; ssq[t] = sq;
    __syncthreads();
    const float rsum = ssum[r] + ssum[r + 128];
    const float rsq  = ssq[r]  + ssq[r + 128];
    const float mean = rsum * (1.0f / DD);
    const float var  = rsq * (1.0f / DD) - mean * mean;
    const float rs   = rsqrtf(fmaxf(var, 0.0f) + 1e-5f);

    // pass 2: normalize + write (same coalesced pattern; L2-hot re-read)
    for (int tile = 0; tile < 32; ++tile) {
        #pragma unroll
        for (int qq = 0; qq < 2; ++qq) {
            const int q = h * 2 + qq;
            const int kbase = tile * 32 + q * 8;
            f16* p = base + tile * 4096 + q * 1024 + r * 8;
            const f16x8 v = *reinterpret_cast<const f16x8*>(p);
            f16 o[8];
            #pragma unroll
            for (int j = 0; j < 8; ++j)
                o[j] = (f16)(((float)v[j] - mean) * rs * gs[kbase + j] + bs[kbase + j]);
            *reinterpret_cast<f16x8*>(p) = *reinterpret_cast<f16x8*>(o);
        }
    }
}

// ---------------------------------------------------------------------------
// Row softmax over 512 cols, fp32 in -> packed fp16 (K=512)
// ---------------------------------------------------------------------------
__global__ __launch_bounds__(256) void softmax512_h_kernel(
    const float* __restrict__ x, f16* __restrict__ o)
{
    const long long row = blockIdx.x;
    const float2 v = reinterpret_cast<const float2*>(x + row * 512)[threadIdx.x];
    const int t = threadIdx.x;

    __shared__ float red[4];
    float mx = fmaxf(v.x, v.y);
    #pragma unroll
    for (int off = 32; off; off >>= 1) mx = fmaxf(mx, __shfl_down(mx, off));
    if ((t & 63) == 0) red[t >> 6] = mx;
    __syncthreads();
    mx = fmaxf(fmaxf(red[0], red[1]), fmaxf(red[2], red[3]));
    __syncthreads();

    const float e0 = expf(v.x - mx), e1 = expf(v.y - mx);
    float s = e0 + e1;
    #pragma unroll
    for (int off = 32; off; off >>= 1) s += __shfl_down(s, off);
    if ((t & 63) == 0) red[t >> 6] = s;
    __syncthreads();
    s = red[0] + red[1] + red[2] + red[3];
    const float inv = 1.0f / s;

    f16 p[2] = {(f16)(e0 * inv), (f16)(e1 * inv)};
    *reinterpret_cast<f16x2*>(&o[paddr(row, 2 * t, 512)]) =
        *reinterpret_cast<f16x2*>(p);
}

// fp32 row softmax over 512 in place (pool weights)
__global__ __launch_bounds__(256) void softmax512_kernel(float* __restrict__ x)
{
    const long long row = blockIdx.x;
    float2* xr = reinterpret_cast<float2*>(x + row * 512);
    const int t = threadIdx.x;
    float2 v = xr[t];

    __shared__ float red[4];
    float mx = fmaxf(v.x, v.y);
    #pragma unroll
    for (int off = 32; off; off >>= 1) mx = fmaxf(mx, __shfl_down(mx, off));
    if ((t & 63) == 0) red[t >> 6] = mx;
    __syncthreads();
    mx = fmaxf(fmaxf(red[0], red[1]), fmaxf(red[2], red[3]));
    __syncthreads();

    const float e0 = expf(v.x - mx), e1 = expf(v.y - mx);
    float s = e0 + e1;
    #pragma unroll
    for (int off = 32; off; off >>= 1) s += __shfl_down(s, off);
    if ((t & 63) == 0) red[t >> 6] = s;
    __syncthreads();
    s = red[0] + red[1] + red[2] + red[3];
    const float inv = 1.0f / s;
    xr[t] = make_float2(e0 * inv, e1 * inv);
}

// ---------------------------------------------------------------------------
// fp32 tiled GEMM (kept for the small fc head ops)
// ---------------------------------------------------------------------------
#define BM 64
#define BN 64
#define BK 16

template <int TA, int TB, int ACT>
__global__ __launch_bounds__(256) void gemm_kernel(
    const float* __restrict__ A, const float* __restrict__ B,
    const float* __restrict__ bias, const float* __restrict__ add_const_ptr,
    float* __restrict__ C,
    int M, int N, int K,
    long long strideA, long long strideB, long long strideC,
    float alpha)
{
    const int batch = blockIdx.z;
    A += (long long)batch * strideA;
    B += (long long)batch * strideB;
    C += (long long)batch * strideC;

    __shared__ float As[BK][BM + 4];
    __shared__ float Bs[BK][BN + 4];

    const int t  = threadIdx.x;
    const int tx = t & 15;
    const int ty = t >> 4;
    const int m0 = blockIdx.y * BM;
    const int n0 = blockIdx.x * BN;

    float acc[4][4] = {};

    for (int k0 = 0; k0 < K; k0 += BK) {
        if (TA == 0) {
            const int mm = t >> 2;
            const int kk = (t & 3) * 4;
            const float4 v = *reinterpret_cast<const float4*>(
                &A[(long long)(m0 + mm) * K + (k0 + kk)]);
            As[kk + 0][mm] = v.x; As[kk + 1][mm] = v.y;
            As[kk + 2][mm] = v.z; As[kk + 3][mm] = v.w;
        } else {
            const int kk = t >> 4;
            const int mm = (t & 15) * 4;
            const float4 v = *reinterpret_cast<const float4*>(
                &A[(long long)(k0 + kk) * M + (m0 + mm)]);
            *reinterpret_cast<float4*>(&As[kk][mm]) = v;
        }
        if (TB == 0) {
            const int kk = t >> 4;
            const int nn = (t & 15) * 4;
            const float4 v = *reinterpret_cast<const float4*>(
                &B[(long long)(k0 + kk) * N + (n0 + nn)]);
            *reinterpret_cast<float4*>(&Bs[kk][nn]) = v;
        } else {
            const int nn = t >> 2;
            const int kk = (t & 3) * 4;
            const float4 v = *reinterpret_cast<const float4*>(
                &B[(long long)(n0 + nn) * K + (k0 + kk)]);
            Bs[kk + 0][nn] = v.x; Bs[kk + 1][nn] = v.y;
            Bs[kk + 2][nn] = v.z; Bs[kk + 3][nn] = v.w;
        }
        __syncthreads();

        #pragma unroll
        for (int kk = 0; kk < BK; ++kk) {
            float a[4], b[4];
            #pragma unroll
            for (int i = 0; i < 4; ++i) a[i] = As[kk][ty * 4 + i];
            #pragma unroll
            for (int j = 0; j < 4; ++j) b[j] = Bs[kk][tx * 4 + j];
            #pragma unroll
            for (int i = 0; i < 4; ++i)
                #pragma unroll
                for (int j = 0; j < 4; ++j)
                    acc[i][j] = fmaf(a[i], b[j], acc[i][j]);
        }
        __syncthreads();
    }

    const float cadd = add_const_ptr ? add_const_ptr[0] : 0.0f;
    #pragma unroll
    for (int i = 0; i < 4; ++i) {
        const int m = m0 + ty * 4 + i;
        #pragma unroll
        for (int j = 0; j < 4; ++j) {
            const int n = n0 + tx * 4 + j;
            float v = acc[i][j] * alpha + cadd;
            if (bias) v += bias[n];
            if (ACT == 1) v = (v > 0.0f) ? v : 0.01f * v;
            else if (ACT == 2) v = 0.5f * v * (1.0f + erff(v * 0.70710678118654752f));
            C[(long long)m * N + n] = v;
        }
    }
}

// pool_scores[row] = h[row,:64] . Wp2 + bp2   (h row stride = 128)
__global__ __launch_bounds__(256) void pool_score_kernel(
    const float* __restrict__ h, const float* __restrict__ Wp2,
    const float* __restrict__ bp2, float* __restrict__ out)
{
    const int row  = blockIdx.x * 4 + (threadIdx.x >> 6);
    const int lane = threadIdx.x & 63;
    float v = h[(long long)row * 128 + lane] * Wp2[lane];
    #pragma unroll
    for (int off = 32; off; off >>= 1) v += __shfl_down(v, off);
    if (lane == 0) out[row] = v + bp2[0];
}

// pooled[b,d] = sum_n fused[b,n,d] * w[b,n]   (fused = packed f16, K=1024)
__global__ __launch_bounds__(256) void pooled_kernel(
    const f16* __restrict__ fused, const float* __restrict__ w,
    float* __restrict__ out)
{
    const int b = blockIdx.y;
    const int d = blockIdx.x * 256 + threadIdx.x;
    __shared__ float ws_[CC_];
    for (int i = threadIdx.x; i < CC_; i += 256) ws_[i] = w[(long long)b * CC_ + i];
    __syncthreads();
    const long long dpart = (long long)(d >> 5) * 4096
                          + ((d >> 3) & 3) * 1024 + (d & 7);
    float acc = 0.0f;
    for (int n = 0; n < CC_; ++n) {
        const long long r = (long long)b * CC_ + n;
        const long long addr = ((r >> 7) * 32) * 4096 + dpart + (r & 127) * 8;
        acc = fmaf((float)fused[addr], ws_[n], acc);
    }
    out[(long long)b * DD + d] = acc;
}

// rul[b] = |h2[b,:] . Wf3 + bf3|
__global__ __launch_bounds__(256) void rul_kernel(
    const float* __restrict__ h2, const float* __restrict__ Wf3,
    const float* __restrict__ bf3, float* __restrict__ out)
{
    const int b = blockIdx.x;
    const int t = threadIdx.x;
    float acc = 0.0f;
    for (int k = t; k < DF_; k += 256)
        acc = fmaf(h2[(long long)b * DF_ + k], Wf3[k], acc);
    __shared__ float red[4];
    #pragma unroll
    for (int off = 32; off; off >>= 1) acc += __shfl_down(acc, off);
    if ((t & 63) == 0) red[t >> 6] = acc;
    __syncthreads();
    if (t == 0) out[b] = fabsf(red[0] + red[1] + red[2] + red[3] + bf3[0]);
}

// ---------------------------------------------------------------------------
// Launch
// ---------------------------------------------------------------------------
extern "C" void kernel_launch(void* const* d_in, const int* in_sizes, int n_in,
                              void* d_out, int out_size, void* d_ws, size_t ws_size,
                              hipStream_t stream)
{
    const float* x_enc   = (const float*)d_in[0];
    const float* W_emb   = (const float*)d_in[2];
    const float* b_emb   = (const float*)d_in[3];
    const float* g_s     = (const float*)d_in[4];
    const float* b_s     = (const float*)d_in[5];
    const float* basis   = (const float*)d_in[6];
    const float* Wq      = (const float*)d_in[7];
    const float* bq      = (const float*)d_in[8];
    const float* Wk      = (const float*)d_in[9];
    const float* bk      = (const float*)d_in[10];
    const float* Wv      = (const float*)d_in[11];
    const float* bv      = (const float*)d_in[12];
    const float* age_sc  = (const float*)d_in[13];
    const float* g_f     = (const float*)d_in[14];
    const float* b_f     = (const float*)d_in[15];
    const float* Wp1     = (const float*)d_in[16];
    const float* bp1     = (const float*)d_in[17];
    const float* Wp2     = (const float*)d_in[18];
    const float* bp2     = (const float*)d_in[19];
    const float* Wf1     = (const float*)d_in[20];
    const float* bf1     = (const float*)d_in[21];
    const float* Wf2     = (const float*)d_in[22];
    const float* bf2     = (const float*)d_in[23];
    const float* Wf3     = (const float*)d_in[24];
    const float* bf3     = (const float*)d_in[25];
    float* out = (float*)d_out;
    (void)in_sizes; (void)n_in; (void)out_size; (void)ws_size;

    // ---- workspace layout (MB offsets, liveness-reused; peak < 896 MB) ----
    const unsigned long long MBy = 1048576ULL;
    char* ws = (char*)d_ws;
    f16*  xT     = (f16*)(ws + 0 * MBy);       // packed [B] r=C,K=T  (dead after sensor)
    f16*  WembT  = (f16*)(ws + 128 * MBy);     // packed r=D,K=T   2 MB
    f16*  WqT    = (f16*)(ws + 130 * MBy);     // packed r=D,K=D   2 MB
    f16*  WkT    = (f16*)(ws + 132 * MBy);
    f16*  WvT    = (f16*)(ws + 134 * MBy);
    f16*  Wp1p   = (f16*)(ws + 136 * MBy);     // packed r=128(pad),K=D
    float* bp1p  = (float*)(ws + 137 * MBy);   // padded bias [128]
    f16*  bas    = (f16*)(ws + 138 * MBy);     // packed r=C,K=D   1 MB
    f16*  sens   = (f16*)(ws + 256 * MBy);     // packed r=BC,K=D  (LN in place)
    f16*  Qp     = (f16*)(ws + 0 * MBy);       // packed r=BC,K=D (xT dead)
    f16*  Kp     = (f16*)(ws + 384 * MBy);     // packed r=BC,K=D
    f16*  S1T    = (f16*)(ws + 512 * MBy);     // packed [B] r=C,K=C  64 MB
    f16*  S2T    = (f16*)(ws + 640 * MBy);     // packed [B] r=C,K=C  64 MB
    float* S3    = (float*)(ws + 704 * MBy);   // [B][C][C] fp32  128 MB
    f16*  attn   = (f16*)(ws + 0 * MBy);       // packed r=BC,K=C (Qp dead)
    f16*  VT     = (f16*)(ws + 384 * MBy);     // packed [B] r=D,K=C (Kp dead)
    f16*  fusedp = (f16*)(ws + 512 * MBy);     // packed r=BC,K=D (S1T dead)
    float* hpool = (float*)(ws + 704 * MBy);   // [BC][128] fp32 (S3 dead)
    float* pscr  = (float*)(ws + 840 * MBy);
    float* pooled= (float*)(ws + 842 * MBy);
    float* h1    = (float*)(ws + 844 * MBy);
    float* h2    = (float*)(ws + 848 * MBy);

    const long long CD  = (long long)CC_ * DD;   // 524288
    const long long CCs = (long long)CC_ * CC_;  // 262144
    const long long DC  = (long long)DD * CC_;
    const dim3 blk(256);

    // ---- upfront prep: all weight packs (independent of pipeline) ----
    transpose_h_kernel<<<dim3(CC_ / 32, TT / 32, BB), blk, 0, stream>>>(
        x_enc, xT, TT, CC_, (long long)TT * CC_, (long long)CC_ * TT);
    transpose_h_kernel<<<dim3(DD / 32, TT / 32, 1), blk, 0, stream>>>(
        W_emb, WembT, TT, DD, 0, 0);
    transpose_h_kernel<<<dim3(DD / 32, DD / 32, 1), blk, 0, stream>>>(
        Wq, WqT, DD, DD, 0, 0);
    transpose_h_kernel<<<dim3(DD / 32, DD / 32, 1), blk, 0, stream>>>(
        Wk, WkT, DD, DD, 0, 0);
    transpose_h_kernel<<<dim3(DD / 32, DD / 32, 1), blk, 0, stream>>>(
        Wv, WvT, DD, DD, 0, 0);
    zero_h_kernel<<<64, blk, 0, stream>>>(Wp1p, 131072);
    transpose_h_kernel<<<dim3(HH / 32, DD / 32, 1), blk, 0, stream>>>(
        Wp1, Wp1p, DD, HH, 0, 0);
    pad_bias_kernel<<<1, 128, 0, stream>>>(bp1, bp1p);
    cvt_h_kernel<<<(CC_ * DD) / 1024, blk, 0, stream>>>(
        basis, bas, (long long)CC_ * DD);

    // ---- main pipeline ----
    // sensor = xT @ WembT^T + b_emb -> packed f16
    mfma_gemm<1><<<dim3(DD / 128, CC_ / 128, BB), blk, 0, stream>>>(
        xT, WembT, b_emb, nullptr, sens,
        CC_, DD, TT, (long long)CC_ * TT, 0, CD, 1.0f);
    layernorm_pg_kernel<<<(BB * CC_) / 128, blk, 0, stream>>>(sens, g_s, b_s);
    // Q = sensor @ Wq + bq -> packed
    mfma_gemm<1><<<dim3(DD / 128, (BB * CC_) / 128, 1), blk, 0, stream>>>(
        sens, WqT, bq, nullptr, Qp,
        BB * CC_, DD, DD, 0, 0, 0, 1.0f);
    // K = sensor @ Wk + bk -> packed
    mfma_gemm<1><<<dim3(DD / 128, (BB * CC_) / 128, 1), blk, 0, stream>>>(
        sens, WkT, bk, nullptr, Kp,
        BB * CC_, DD, DD, 0, 0, 0, 1.0f);
    // S1T = (Q K^T / 32 + age)^T packed (rows C, K=C) per batch
    mfma_gemm<2><<<dim3(CC_ / 128, CC_ / 128, BB), blk, 0, stream>>>(
        Qp, Kp, nullptr, age_sc, S1T,
        CC_, CC_, DD, CD, CD, CCs, INV_SQRT_D);
    // S2T = (Q basis^T / 32)^T packed
    mfma_gemm<2><<<dim3(CC_ / 128, CC_ / 128, BB), blk, 0, stream>>>(
        Qp, bas, nullptr, nullptr, S2T,
        CC_, CC_, DD, CD, 0, CCs, INV_SQRT_D);
    // S3[n,k] = sum_j S2T[n,j]*S1T[k,j]   (fp32 out)
    mfma_gemm<0><<<dim3(CC_ / 128, CC_ / 128, BB), blk, 0, stream>>>(
        S2T, S1T, nullptr, nullptr, S3,
        CC_, CC_, CC_, CCs, CCs, CCs, 1.0f);
    // attn = softmax(S3) -> packed fp16 (rows flat BC, K=C)
    softmax512_h_kernel<<<BB * CC_, blk, 0, stream>>>(S3, attn);
    // VT = (sensor @ Wv + bv)^T packed (rows D, K=C) per batch
    mfma_gemm<2><<<dim3(DD / 128, CC_ / 128, BB), blk, 0, stream>>>(
        sens, WvT, bv, nullptr, VT,
        CC_, DD, DD, CD, 0, DC, 1.0f);
    // fused = attn @ VT^T / 32 -> packed f16 (rows flat BC, K=D)
    mfma_gemm<1><<<dim3(DD / 128, CC_ / 128, BB), blk, 0, stream>>>(
        attn, VT, nullptr, nullptr, fusedp,
        CC_, DD, CC_, CCs, DC, CD, INV_SQRT_D);
    layernorm_pg_kernel<<<(BB * CC_) / 128, blk, 0, stream>>>(fusedp, g_f, b_f);
    // hpool = gelu(fused @ Wp1 + bp1)  (MFMA, padded N=128)
    mfma_gemm<0, 2><<<dim3(1, (BB * CC_) / 128, 1), blk, 0, stream>>>(
        fusedp, Wp1p, bp1p, nullptr, hpool,
        BB * CC_, 128, DD, 0, 0, 0, 1.0f);
    // pool scores + softmax over C
    pool_score_kernel<<<(BB * CC_) / 4, blk, 0, stream>>>(hpool, Wp2, bp2, pscr);
    softmax512_kernel<<<BB, blk, 0, stream>>>(pscr);
    // pooled (reads packed fused)
    pooled_kernel<<<dim3(DD / 256, BB), blk, 0, stream>>>(fusedp, pscr, pooled);
    // fc head
    gemm_kernel<0, 0, 1><<<dim3(DF_ / 64, BB / 64, 1), blk, 0, stream>>>(
        pooled, Wf1, bf1, nullptr, h1, BB, DF_, DD, 0, 0, 0, 1.0f);
    gemm_kernel<0, 0, 0><<<dim3(DF_ / 64, BB / 64, 1), blk, 0, stream>>>(
        h1, Wf2, bf2, nullptr, h2, BB, DF_, DF_, 0, 0, 0, 1.0f);
    rul_kernel<<<BB, blk, 0, stream>>>(h2, Wf3, bf3, out);
}

// Round 18
// 1477.554 us; speedup vs baseline: 1.0645x; 1.0645x over previous
//
#include <hip/hip_runtime.h>
#include <hip/hip_bf16.h>
#include <math.h>

// ---------------------------------------------------------------------------
// Problem constants
// ---------------------------------------------------------------------------
#define BB   128     // batch
#define TT   1024    // time
#define CC_  512     // channels / variates (N)
#define DD   1024    // model dim
#define DF_  2048    // fc hidden
#define HH   64      // pool hidden
#define INV_SQRT_D 0.03125f   // 1/sqrt(1024)

typedef _Float16 f16;
typedef __attribute__((ext_vector_type(8))) _Float16 f16x8;
typedef __attribute__((ext_vector_type(4))) _Float16 f16x4;
typedef __attribute__((ext_vector_type(2))) _Float16 f16x2;
typedef __attribute__((ext_vector_type(4))) float f32x4;

__device__ __forceinline__ void gload_lds16(const void* g, void* l) {
    // async global->LDS, 16B per lane; LDS dest = wave-uniform base + lane*16
    __builtin_amdgcn_global_load_lds(
        (const __attribute__((address_space(1))) void*)g,
        (__attribute__((address_space(3))) void*)l, 16, 0, 0);
}

// Tile-packed operand layout (half-element index).  For a GEMM operand with
// row dim r (tiles of 128) and contraction dim k (tiles of 32, sub-chunks
// of 8): element (r,k) lives at
//   ((r>>7)*(K>>5) + (k>>5))*4096 + ((k>>3)&3)*1024 + (r&127)*8 + (k&7)
__device__ __forceinline__ long long paddr(long long r, int k, int K) {
    return ((r >> 7) * (long long)(K >> 5) + (k >> 5)) * 4096LL
         + (long long)(((k >> 3) & 3) * 1024 + ((int)(r & 127)) * 8 + (k & 7));
}

// ---------------------------------------------------------------------------
// fp16 MFMA GEMM (fp32 accumulate), 128x128 tile, BK=64, 4 waves,
// single-buffered 2-barrier loop, PACKED operands.
//   C[m,n] = act(alpha*sum_k A[m,k]*B[n,k] + add_c + bias[n])
//   OUT: 0 = fp32 C[M][N] row-major;  1 = packed f16 (r=m, k=n, K=N);
//        2 = packed f16 transposed (r=n, k=m, K=M)
//   ACT: 0 = none, 2 = exact gelu
// M,N multiples of 128; K multiple of 64.
// ---------------------------------------------------------------------------
template <int OUT, int ACT = 0>
__global__ __launch_bounds__(256, 4) void mfma_gemm(
    const f16* __restrict__ A, const f16* __restrict__ B,
    const float* __restrict__ bias, const float* __restrict__ add_c,
    void* __restrict__ C0,
    int M, int N, int K,
    long long sA, long long sB, long long sC, float alpha)
{
    // ---- XCD swizzle on flattened (x,y); identity when nwg % 8 != 0 ----
    const int gx = gridDim.x;
    const int nwg = gx * gridDim.y;
    int lin = blockIdx.y * gx + blockIdx.x;
    if ((nwg & 7) == 0) {
        const int cpx = nwg >> 3;
        lin = (lin & 7) * cpx + (lin >> 3);
    }
    const int bx = lin % gx, by = lin / gx;

    const int bz   = blockIdx.z;
    const int t    = threadIdx.x;
    const int wave = t >> 6, lane = t & 63;
    const int m0 = by * 128, n0 = bx * 128;
    const int wm = (wave >> 1) * 64, wn = (wave & 1) * 64;

    __shared__ __align__(16) f16 As[2][4096];   // 8 KB per sub-tile
    __shared__ __align__(16) f16 Bs[2][4096];

    f32x4 acc[4][4] = {};

    const int wbyte = wave * 1024;               // wave-uniform LDS base
    const long long tA = (long long)bz * sA + (long long)(m0 >> 7) * (K >> 5) * 4096;
    const long long tB = (long long)bz * sB + (long long)(n0 >> 7) * (K >> 5) * 4096;
    const f16* pA = A + tA + t * 8;
    const f16* pB = B + tB + t * 8;

    const int q   = lane >> 4;   // k-chunk for fragment reads
    const int r16 = lane & 15;

    for (int k0 = 0; k0 < K; k0 += 64) {
        const long long ko = (long long)(k0 >> 5) * 4096;
        __syncthreads();                       // previous compute done
        gload_lds16(pA + ko,        (char*)(&As[0][0]) + wbyte);
        gload_lds16(pA + ko + 2048, (char*)(&As[0][0]) + wbyte + 4096);
        gload_lds16(pA + ko + 4096, (char*)(&As[1][0]) + wbyte);
        gload_lds16(pA + ko + 6144, (char*)(&As[1][0]) + wbyte + 4096);
        gload_lds16(pB + ko,        (char*)(&Bs[0][0]) + wbyte);
        gload_lds16(pB + ko + 2048, (char*)(&Bs[0][0]) + wbyte + 4096);
        gload_lds16(pB + ko + 4096, (char*)(&Bs[1][0]) + wbyte);
        gload_lds16(pB + ko + 6144, (char*)(&Bs[1][0]) + wbyte + 4096);
        __syncthreads();                       // drains vmcnt: tiles ready

        #pragma unroll
        for (int s = 0; s < 2; ++s) {
            const f16x8* AV = (const f16x8*)(&As[s][0]);
            const f16x8* BV = (const f16x8*)(&Bs[s][0]);
            f16x8 bfr[4];
            #pragma unroll
            for (int j = 0; j < 4; ++j)
                bfr[j] = BV[q * 128 + wn + j * 16 + r16];
            __builtin_amdgcn_s_setprio(1);
            #pragma unroll
            for (int i = 0; i < 4; ++i) {
                const f16x8 a = AV[q * 128 + wm + i * 16 + r16];
                #pragma unroll
                for (int j = 0; j < 4; ++j)
                    acc[i][j] = __builtin_amdgcn_mfma_f32_16x16x32_f16(
                        a, bfr[j], acc[i][j], 0, 0, 0);
            }
            __builtin_amdgcn_s_setprio(0);
        }
    }

    // epilogue: C/D layout col = lane&15, row = (lane>>4)*4 + r
    const float cadd = add_c ? add_c[0] : 0.0f;
    const int col = lane & 15;
    const int rb  = (lane >> 4) * 4;
    #pragma unroll
    for (int j = 0; j < 4; ++j) {
        const int n = n0 + wn + j * 16 + col;
        const float bv = bias ? bias[n] : 0.0f;
        #pragma unroll
        for (int i = 0; i < 4; ++i) {
            const int m = m0 + wm + i * 16 + rb;
            f32x4 v = acc[i][j];
            #pragma unroll
            for (int r = 0; r < 4; ++r) {
                v[r] = v[r] * alpha + cadd + bv;
                if constexpr (ACT == 2)
                    v[r] = 0.5f * v[r] * (1.0f + erff(v[r] * 0.70710678118654752f));
            }
            if constexpr (OUT == 0) {
                float* C = (float*)C0 + (long long)bz * sC;
                #pragma unroll
                for (int r = 0; r < 4; ++r) C[(long long)(m + r) * N + n] = v[r];
            } else if constexpr (OUT == 1) {
                // packed: (r=m+r, k=n), K=N
                f16* C = (f16*)C0 + (long long)bz * sC;
                #pragma unroll
                for (int r = 0; r < 4; ++r)
                    C[paddr(m + r, n, N)] = (f16)v[r];
            } else {
                // packed transposed: (r=n, k=m..m+3), K=M;  m%8 in {0,4}
                f16* C = (f16*)C0 + (long long)bz * sC;
                f16 p[4];
                #pragma unroll
                for (int r = 0; r < 4; ++r) p[r] = (f16)v[r];
                *reinterpret_cast<f16x4*>(&C[paddr(n, m, M)]) =
                    *reinterpret_cast<f16x4*>(p);
            }
        }
    }
}

// ---------------------------------------------------------------------------
// fp32 [R][Cc] -> packed fp16 (rows = Cc-dim, k = original row dim, len R).
// value for output (row c0+c, k r0+8q+j) = tile[8q+j][c].
// ---------------------------------------------------------------------------
__global__ __launch_bounds__(256) void transpose_h_kernel(
    const float* __restrict__ in, f16* __restrict__ o,
    int R, int Cc, long long sIn, long long sOut)
{
    const int b = blockIdx.z;
    in += (long long)b * sIn; o += (long long)b * sOut;
    __shared__ float tile[32][33];
    const int c0 = blockIdx.x * 32, r0 = blockIdx.y * 32;
    const int tx = threadIdx.x & 31, ty = threadIdx.x >> 5;   // 32 x 8
    #pragma unroll
    for (int i = 0; i < 32; i += 8)
        tile[ty + i][tx] = in[(long long)(r0 + ty + i) * Cc + (c0 + tx)];
    __syncthreads();
    if (threadIdx.x < 128) {
        const int c = threadIdx.x & 31, q = threadIdx.x >> 5;
        f16 p[8];
        #pragma unroll
        for (int j = 0; j < 8; ++j) p[j] = (f16)tile[8 * q + j][c];
        const long long base =
            (((long long)(c0 + c) >> 7) * (long long)(R >> 5) + (r0 >> 5)) * 4096LL
            + q * 1024 + ((c0 + c) & 127) * 8;
        *reinterpret_cast<f16x8*>(&o[base]) = *reinterpret_cast<f16x8*>(p);
    }
}

// fp32 [R][1024] -> packed fp16 (K=1024), row-major pack (no transpose)
__global__ __launch_bounds__(256) void cvt_h_kernel(
    const float* __restrict__ in, f16* __restrict__ o, long long n)
{
    const long long i = ((long long)blockIdx.x * 256 + threadIdx.x) * 4;
    if (i >= n) return;
    const float4 v = *reinterpret_cast<const float4*>(in + i);
    f16 p[4] = {(f16)v.x, (f16)v.y, (f16)v.z, (f16)v.w};
    const long long r = i >> 10;
    const int k = (int)(i & 1023);
    *reinterpret_cast<f16x4*>(&o[paddr(r, k, 1024)]) = *reinterpret_cast<f16x4*>(p);
}

// zero-fill f16 buffer (n halves, multiple of 2048)
__global__ __launch_bounds__(256) void zero_h_kernel(f16* __restrict__ p, long long n)
{
    const long long i = ((long long)blockIdx.x * 256 + threadIdx.x) * 8;
    if (i >= n) return;
    f16x8 z = {};
    *reinterpret_cast<f16x8*>(p + i) = z;
}

// bias pad: out[0..63]=in, out[64..127]=0
__global__ __launch_bounds__(128) void pad_bias_kernel(
    const float* __restrict__ in, float* __restrict__ o)
{
    const int i = threadIdx.x;
    o[i] = (i < HH) ? in[i] : 0.0f;
}

// out[r] = scale * dot(W[r, 0:1024], v[0:1024]);  one wave per row
__global__ __launch_bounds__(256) void rowdot_kernel(
    const float* __restrict__ W, const float* __restrict__ v,
    float* __restrict__ out, float scale)
{
    const int row  = blockIdx.x * 4 + (threadIdx.x >> 6);
    const int lane = threadIdx.x & 63;
    const float* wr = W + (long long)row * 1024;
    float s = 0.0f;
    for (int k = lane; k < 1024; k += 64) s += wr[k] * v[k];
    #pragma unroll
    for (int off = 32; off; off >>= 1) s += __shfl_down(s, off);
    if (lane == 0) out[row] = s * scale;
}

// ---------------------------------------------------------------------------
// LayerNorm over K=1024 on PACKED f16, in place, COALESCED.
// One block = one 128-row group (32 tiles x 4096 halves = 256 KB contiguous).
// ---------------------------------------------------------------------------
__global__ __launch_bounds__(256) void layernorm_pg_kernel(
    f16* __restrict__ x, const float* __restrict__ g, const float* __restrict__ b)
{
    f16* base = x + (long long)blockIdx.x * 131072;   // 128 rows * 1024 k
    const int t = threadIdx.x;
    const int r = t & 127;
    const int h = t >> 7;

    __shared__ float gs[1024], bs[1024];
    __shared__ float ssum[256], ssq[256];
    for (int i = t; i < 1024; i += 256) { gs[i] = g[i]; bs[i] = b[i]; }

    float sum = 0.0f, sq = 0.0f;
    for (int tile = 0; tile < 32; ++tile) {
        #pragma unroll
        for (int qq = 0; qq < 2; ++qq) {
            const f16x8 v = *reinterpret_cast<const f16x8*>(
                base + tile * 4096 + (h * 2 + qq) * 1024 + r * 8);
            #pragma unroll
            for (int j = 0; j < 8; ++j) {
                const float f = (float)v[j];
                sum += f; sq += f * f;
            }
        }
    }
    ssum[t] = sum; ssq[t] = sq;
    __syncthreads();
    const float rsum = ssum[r] + ssum[r + 128];
    const float rsq  = ssq[r]  + ssq[r + 128];
    const float mean = rsum * (1.0f / DD);
    const float var  = rsq * (1.0f / DD) - mean * mean;
    const float rs   = rsqrtf(fmaxf(var, 0.0f) + 1e-5f);

    for (int tile = 0; tile < 32; ++tile) {
        #pragma unroll
        for (int qq = 0; qq < 2; ++qq) {
            const int q = h * 2 + qq;
            const int kbase = tile * 32 + q * 8;
            f16* p = base + tile * 4096 + q * 1024 + r * 8;
            const f16x8 v = *reinterpret_cast<const f16x8*>(p);
            f16 o[8];
            #pragma unroll
            for (int j = 0; j < 8; ++j)
                o[j] = (f16)(((float)v[j] - mean) * rs * gs[kbase + j] + bs[kbase + j]);
            *reinterpret_cast<f16x8*>(p) = *reinterpret_cast<f16x8*>(o);
        }
    }
}

// ---------------------------------------------------------------------------
// Row softmax over 512 cols, fp32 in -> packed fp16 (K=512)
// ---------------------------------------------------------------------------
__global__ __launch_bounds__(256) void softmax512_h_kernel(
    const float* __restrict__ x, f16* __restrict__ o)
{
    const long long row = blockIdx.x;
    const float2 v = reinterpret_cast<const float2*>(x + row * 512)[threadIdx.x];
    const int t = threadIdx.x;

    __shared__ float red[4];
    float mx = fmaxf(v.x, v.y);
    #pragma unroll
    for (int off = 32; off; off >>= 1) mx = fmaxf(mx, __shfl_down(mx, off));
    if ((t & 63) == 0) red[t >> 6] = mx;
    __syncthreads();
    mx = fmaxf(fmaxf(red[0], red[1]), fmaxf(red[2], red[3]));
    __syncthreads();

    const float e0 = expf(v.x - mx), e1 = expf(v.y - mx);
    float s = e0 + e1;
    #pragma unroll
    for (int off = 32; off; off >>= 1) s += __shfl_down(s, off);
    if ((t & 63) == 0) red[t >> 6] = s;
    __syncthreads();
    s = red[0] + red[1] + red[2] + red[3];
    const float inv = 1.0f / s;

    f16 p[2] = {(f16)(e0 * inv), (f16)(e1 * inv)};
    *reinterpret_cast<f16x2*>(&o[paddr(row, 2 * t, 512)]) =
        *reinterpret_cast<f16x2*>(p);
}

// fp32 row softmax over 512 in place (pool weights)
__global__ __launch_bounds__(256) void softmax512_kernel(float* __restrict__ x)
{
    const long long row = blockIdx.x;
    float2* xr = reinterpret_cast<float2*>(x + row * 512);
    const int t = threadIdx.x;
    float2 v = xr[t];

    __shared__ float red[4];
    float mx = fmaxf(v.x, v.y);
    #pragma unroll
    for (int off = 32; off; off >>= 1) mx = fmaxf(mx, __shfl_down(mx, off));
    if ((t & 63) == 0) red[t >> 6] = mx;
    __syncthreads();
    mx = fmaxf(fmaxf(red[0], red[1]), fmaxf(red[2], red[3]));
    __syncthreads();

    const float e0 = expf(v.x - mx), e1 = expf(v.y - mx);
    float s = e0 + e1;
    #pragma unroll
    for (int off = 32; off; off >>= 1) s += __shfl_down(s, off);
    if ((t & 63) == 0) red[t >> 6] = s;
    __syncthreads();
    s = red[0] + red[1] + red[2] + red[3];
    const float inv = 1.0f / s;
    xr[t] = make_float2(e0 * inv, e1 * inv);
}

// ---------------------------------------------------------------------------
// fp32 tiled GEMM (kept for the small fc head ops)
// ---------------------------------------------------------------------------
#define BM 64
#define BN 64
#define BK 16

template <int TA, int TB, int ACT>
__global__ __launch_bounds__(256) void gemm_kernel(
    const float* __restrict__ A, const float* __restrict__ B,
    const float* __restrict__ bias, const float* __restrict__ add_const_ptr,
    float* __restrict__ C,
    int M, int N, int K,
    long long strideA, long long strideB, long long strideC,
    float alpha)
{
    const int batch = blockIdx.z;
    A += (long long)batch * strideA;
    B += (long long)batch * strideB;
    C += (long long)batch * strideC;

    __shared__ float As[BK][BM + 4];
    __shared__ float Bs[BK][BN + 4];

    const int t  = threadIdx.x;
    const int tx = t & 15;
    const int ty = t >> 4;
    const int m0 = blockIdx.y * BM;
    const int n0 = blockIdx.x * BN;

    float acc[4][4] = {};

    for (int k0 = 0; k0 < K; k0 += BK) {
        if (TA == 0) {
            const int mm = t >> 2;
            const int kk = (t & 3) * 4;
            const float4 v = *reinterpret_cast<const float4*>(
                &A[(long long)(m0 + mm) * K + (k0 + kk)]);
            As[kk + 0][mm] = v.x; As[kk + 1][mm] = v.y;
            As[kk + 2][mm] = v.z; As[kk + 3][mm] = v.w;
        } else {
            const int kk = t >> 4;
            const int mm = (t & 15) * 4;
            const float4 v = *reinterpret_cast<const float4*>(
                &A[(long long)(k0 + kk) * M + (m0 + mm)]);
            *reinterpret_cast<float4*>(&As[kk][mm]) = v;
        }
        if (TB == 0) {
            const int kk = t >> 4;
            const int nn = (t & 15) * 4;
            const float4 v = *reinterpret_cast<const float4*>(
                &B[(long long)(k0 + kk) * N + (n0 + nn)]);
            *reinterpret_cast<float4*>(&Bs[kk][nn]) = v;
        } else {
            const int nn = t >> 2;
            const int kk = (t & 3) * 4;
            const float4 v = *reinterpret_cast<const float4*>(
                &B[(long long)(n0 + nn) * K + (k0 + kk)]);
            Bs[kk + 0][nn] = v.x; Bs[kk + 1][nn] = v.y;
            Bs[kk + 2][nn] = v.z; Bs[kk + 3][nn] = v.w;
        }
        __syncthreads();

        #pragma unroll
        for (int kk = 0; kk < BK; ++kk) {
            float a[4], b[4];
            #pragma unroll
            for (int i = 0; i < 4; ++i) a[i] = As[kk][ty * 4 + i];
            #pragma unroll
            for (int j = 0; j < 4; ++j) b[j] = Bs[kk][tx * 4 + j];
            #pragma unroll
            for (int i = 0; i < 4; ++i)
                #pragma unroll
                for (int j = 0; j < 4; ++j)
                    acc[i][j] = fmaf(a[i], b[j], acc[i][j]);
        }
        __syncthreads();
    }

    const float cadd = add_const_ptr ? add_const_ptr[0] : 0.0f;
    #pragma unroll
    for (int i = 0; i < 4; ++i) {
        const int m = m0 + ty * 4 + i;
        #pragma unroll
        for (int j = 0; j < 4; ++j) {
            const int n = n0 + tx * 4 + j;
            float v = acc[i][j] * alpha + cadd;
            if (bias) v += bias[n];
            if (ACT == 1) v = (v > 0.0f) ? v : 0.01f * v;
            else if (ACT == 2) v = 0.5f * v * (1.0f + erff(v * 0.70710678118654752f));
            C[(long long)m * N + n] = v;
        }
    }
}

// pool_scores[row] = h[row,:64] . Wp2 + bp2   (h row stride = 128)
__global__ __launch_bounds__(256) void pool_score_kernel(
    const float* __restrict__ h, const float* __restrict__ Wp2,
    const float* __restrict__ bp2, float* __restrict__ out)
{
    const int row  = blockIdx.x * 4 + (threadIdx.x >> 6);
    const int lane = threadIdx.x & 63;
    float v = h[(long long)row * 128 + lane] * Wp2[lane];
    #pragma unroll
    for (int off = 32; off; off >>= 1) v += __shfl_down(v, off);
    if (lane == 0) out[row] = v + bp2[0];
}

// pooled[b,d] = sum_n fused[b,n,d] * w[b,n]   (fused = packed f16, K=1024)
__global__ __launch_bounds__(256) void pooled_kernel(
    const f16* __restrict__ fused, const float* __restrict__ w,
    float* __restrict__ out)
{
    const int b = blockIdx.y;
    const int d = blockIdx.x * 256 + threadIdx.x;
    __shared__ float ws_[CC_];
    for (int i = threadIdx.x; i < CC_; i += 256) ws_[i] = w[(long long)b * CC_ + i];
    __syncthreads();
    const long long dpart = (long long)(d >> 5) * 4096
                          + ((d >> 3) & 3) * 1024 + (d & 7);
    float acc = 0.0f;
    for (int n = 0; n < CC_; ++n) {
        const long long r = (long long)b * CC_ + n;
        const long long addr = ((r >> 7) * 32) * 4096 + dpart + (r & 127) * 8;
        acc = fmaf((float)fused[addr], ws_[n], acc);
    }
    out[(long long)b * DD + d] = acc;
}

// rul[b] = |h2[b,:] . Wf3 + bf3|
__global__ __launch_bounds__(256) void rul_kernel(
    const float* __restrict__ h2, const float* __restrict__ Wf3,
    const float* __restrict__ bf3, float* __restrict__ out)
{
    const int b = blockIdx.x;
    const int t = threadIdx.x;
    float acc = 0.0f;
    for (int k = t; k < DF_; k += 256)
        acc = fmaf(h2[(long long)b * DF_ + k], Wf3[k], acc);
    __shared__ float red[4];
    #pragma unroll
    for (int off = 32; off; off >>= 1) acc += __shfl_down(acc, off);
    if ((t & 63) == 0) red[t >> 6] = acc;
    __syncthreads();
    if (t == 0) out[b] = fabsf(red[0] + red[1] + red[2] + red[3] + bf3[0]);
}

// ---------------------------------------------------------------------------
// Launch
// ---------------------------------------------------------------------------
extern "C" void kernel_launch(void* const* d_in, const int* in_sizes, int n_in,
                              void* d_out, int out_size, void* d_ws, size_t ws_size,
                              hipStream_t stream)
{
    const float* x_enc   = (const float*)d_in[0];
    const float* W_emb   = (const float*)d_in[2];
    const float* b_emb   = (const float*)d_in[3];
    const float* g_s     = (const float*)d_in[4];
    const float* b_s     = (const float*)d_in[5];
    const float* basis   = (const float*)d_in[6];
    const float* Wq      = (const float*)d_in[7];
    const float* bq      = (const float*)d_in[8];
    const float* Wk      = (const float*)d_in[9];
    // bk (d_in[10]) and age_scale (d_in[13]) drop out of softmax (per-row consts)
    const float* Wv      = (const float*)d_in[11];
    const float* bv      = (const float*)d_in[12];
    const float* g_f     = (const float*)d_in[14];
    const float* b_f     = (const float*)d_in[15];
    const float* Wp1     = (const float*)d_in[16];
    const float* bp1     = (const float*)d_in[17];
    const float* Wp2     = (const float*)d_in[18];
    const float* bp2     = (const float*)d_in[19];
    const float* Wf1     = (const float*)d_in[20];
    const float* bf1     = (const float*)d_in[21];
    const float* Wf2     = (const float*)d_in[22];
    const float* bf2     = (const float*)d_in[23];
    const float* Wf3     = (const float*)d_in[24];
    const float* bf3     = (const float*)d_in[25];
    float* out = (float*)d_out;
    (void)in_sizes; (void)n_in; (void)out_size; (void)ws_size;

    // ---- workspace layout (MB offsets, liveness-reused; peak < 896 MB) ----
    const unsigned long long MBy = 1048576ULL;
    char* ws = (char*)d_ws;
    f16*  xT     = (f16*)(ws + 0 * MBy);       // packed [B] r=C,K=T (dead after sensor)
    f16*  WembT  = (f16*)(ws + 128 * MBy);     // packed r=D,K=T   2 MB
    f16*  Wqc    = (f16*)(ws + 130 * MBy);     // packed r=e(in),K=o  2 MB
    f16*  Wkc    = (f16*)(ws + 132 * MBy);     // packed r=i(in),K=o  2 MB
    f16*  Pt     = (f16*)(ws + 134 * MBy);     // packed r=i,K=e   2 MB (Wq Wk^T)^T
    f16*  W2t    = (f16*)(ws + 136 * MBy);     // packed r=m,K=e   1 MB (Wq bas^T)^T
    f16*  bas    = (f16*)(ws + 137 * MBy);     // packed r=C,K=D   1 MB
    f16*  Wp1p   = (f16*)(ws + 138 * MBy);     // packed r=128(pad),K=D
    float* bp1p  = (float*)(ws + 139 * MBy);   // padded bias [128]
    float* pbias = (float*)(ws + 139 * MBy + 4096);   // [1024]
    float* c2s   = (float*)(ws + 139 * MBy + 16384);  // [512]
    f16*  WvT    = (f16*)(ws + 140 * MBy);     // packed r=D,K=D   2 MB
    f16*  sens   = (f16*)(ws + 256 * MBy);     // packed r=BC,K=D  (LN in place)
    f16*  QWp    = (f16*)(ws + 0 * MBy);       // packed r=BC,K=D (xT dead) 128 MB
    f16*  T1     = (f16*)(ws + 512 * MBy);     // packed [B] r=C,K=C  64 MB
    f16*  S2T    = (f16*)(ws + 640 * MBy);     // packed [B] r=C,K=C  64 MB
    float* S3    = (float*)(ws + 704 * MBy);   // [B][C][C] fp32  128 MB
    f16*  attn   = (f16*)(ws + 0 * MBy);       // packed r=BC,K=C (QWp dead)
    f16*  VT     = (f16*)(ws + 384 * MBy);     // packed [B] r=D,K=C  128 MB
    f16*  fusedp = (f16*)(ws + 512 * MBy);     // packed r=BC,K=D (T1/S2T dead)
    float* hpool = (float*)(ws + 704 * MBy);   // [BC][128] fp32 (S3 dead)
    float* pscr  = (float*)(ws + 840 * MBy);
    float* pooled= (float*)(ws + 842 * MBy);
    float* h1    = (float*)(ws + 844 * MBy);
    float* h2    = (float*)(ws + 848 * MBy);

    const long long CD  = (long long)CC_ * DD;   // 524288
    const long long CCs = (long long)CC_ * CC_;  // 262144
    const long long DC  = (long long)DD * CC_;
    const dim3 blk(256);

    // ---- upfront prep ----
    transpose_h_kernel<<<dim3(CC_ / 32, TT / 32, BB), blk, 0, stream>>>(
        x_enc, xT, TT, CC_, (long long)TT * CC_, (long long)CC_ * TT);
    transpose_h_kernel<<<dim3(DD / 32, TT / 32, 1), blk, 0, stream>>>(
        W_emb, WembT, TT, DD, 0, 0);
    transpose_h_kernel<<<dim3(DD / 32, DD / 32, 1), blk, 0, stream>>>(
        Wv, WvT, DD, DD, 0, 0);
    cvt_h_kernel<<<(DD * DD) / 1024, blk, 0, stream>>>(Wq, Wqc, (long long)DD * DD);
    cvt_h_kernel<<<(DD * DD) / 1024, blk, 0, stream>>>(Wk, Wkc, (long long)DD * DD);
    cvt_h_kernel<<<(CC_ * DD) / 1024, blk, 0, stream>>>(
        basis, bas, (long long)CC_ * DD);
    zero_h_kernel<<<64, blk, 0, stream>>>(Wp1p, 131072);
    transpose_h_kernel<<<dim3(HH / 32, DD / 32, 1), blk, 0, stream>>>(
        Wp1, Wp1p, DD, HH, 0, 0);
    pad_bias_kernel<<<1, 128, 0, stream>>>(bp1, bp1p);
    // pbias[i] = Wk[i,:] . bq ;  c2s[m] = s * (basis[m,:] . bq)
    rowdot_kernel<<<DD / 4, blk, 0, stream>>>(Wk, bq, pbias, 1.0f);
    rowdot_kernel<<<CC_ / 4, blk, 0, stream>>>(basis, bq, c2s, INV_SQRT_D);
    // P^T: P[e,i] = sum_o Wq[e,o] Wk[i,o]; OUT=2 -> packed(r=i, k=e)
    mfma_gemm<2><<<dim3(DD / 128, DD / 128, 1), blk, 0, stream>>>(
        Wqc, Wkc, nullptr, nullptr, Pt, DD, DD, DD, 0, 0, 0, 1.0f);
    // W2^T: W2[e,m] = sum_o Wq[e,o] bas[m,o]; OUT=2 -> packed(r=m, k=e)
    mfma_gemm<2><<<dim3(CC_ / 128, DD / 128, 1), blk, 0, stream>>>(
        Wqc, bas, nullptr, nullptr, W2t, DD, CC_, DD, 0, 0, 0, 1.0f);

    // ---- main pipeline ----
    // sensor = xT @ WembT^T + b_emb -> packed f16
    mfma_gemm<1><<<dim3(DD / 128, CC_ / 128, BB), blk, 0, stream>>>(
        xT, WembT, b_emb, nullptr, sens,
        CC_, DD, TT, (long long)CC_ * TT, 0, CD, 1.0f);
    layernorm_pg_kernel<<<(BB * CC_) / 128, blk, 0, stream>>>(sens, g_s, b_s);
    // QW = sens @ P + pbias -> packed (r=BC, K=D)   [= Q Wk^T exactly]
    mfma_gemm<1><<<dim3(DD / 128, (BB * CC_) / 128, 1), blk, 0, stream>>>(
        sens, Pt, pbias, nullptr, QWp,
        BB * CC_, DD, DD, 0, 0, 0, 1.0f);
    // S2T = (s*(sens @ W2) + s*c2)^T packed (rows m, K=C) per batch [= age_bias^T]
    mfma_gemm<2><<<dim3(CC_ / 128, CC_ / 128, BB), blk, 0, stream>>>(
        sens, W2t, c2s, nullptr, S2T,
        CC_, CC_, DD, CD, 0, CCs, INV_SQRT_D);
    // T1 = (s * QW @ sens^T)^T packed (rows k, K=C) per batch
    mfma_gemm<2><<<dim3(CC_ / 128, CC_ / 128, BB), blk, 0, stream>>>(
        QWp, sens, nullptr, nullptr, T1,
        CC_, CC_, DD, CD, CD, CCs, INV_SQRT_D);
    // S3[n,k] = sum_j S2T[n,j]*T1[k,j]   (fp32 out)
    mfma_gemm<0><<<dim3(CC_ / 128, CC_ / 128, BB), blk, 0, stream>>>(
        S2T, T1, nullptr, nullptr, S3,
        CC_, CC_, CC_, CCs, CCs, CCs, 1.0f);
    // attn = softmax(S3) -> packed fp16 (rows flat BC, K=C)
    softmax512_h_kernel<<<BB * CC_, blk, 0, stream>>>(S3, attn);
    // VT = (sensor @ Wv + bv)^T packed (rows D, K=C) per batch
    mfma_gemm<2><<<dim3(DD / 128, CC_ / 128, BB), blk, 0, stream>>>(
        sens, WvT, bv, nullptr, VT,
        CC_, DD, DD, CD, 0, DC, 1.0f);
    // fused = attn @ VT^T / 32 -> packed f16 (rows flat BC, K=D)
    mfma_gemm<1><<<dim3(DD / 128, CC_ / 128, BB), blk, 0, stream>>>(
        attn, VT, nullptr, nullptr, fusedp,
        CC_, DD, CC_, CCs, DC, CD, INV_SQRT_D);
    layernorm_pg_kernel<<<(BB * CC_) / 128, blk, 0, stream>>>(fusedp, g_f, b_f);
    // hpool = gelu(fused @ Wp1 + bp1)  (MFMA, padded N=128)
    mfma_gemm<0, 2><<<dim3(1, (BB * CC_) / 128, 1), blk, 0, stream>>>(
        fusedp, Wp1p, bp1p, nullptr, hpool,
        BB * CC_, 128, DD, 0, 0, 0, 1.0f);
    // pool scores + softmax over C
    pool_score_kernel<<<(BB * CC_) / 4, blk, 0, stream>>>(hpool, Wp2, bp2, pscr);
    softmax512_kernel<<<BB, blk, 0, stream>>>(pscr);
    // pooled (reads packed fused)
    pooled_kernel<<<dim3(DD / 256, BB), blk, 0, stream>>>(fusedp, pscr, pooled);
    // fc head
    gemm_kernel<0, 0, 1><<<dim3(DF_ / 64, BB / 64, 1), blk, 0, stream>>>(
        pooled, Wf1, bf1, nullptr, h1, BB, DF_, DD, 0, 0, 0, 1.0f);
    gemm_kernel<0, 0, 0><<<dim3(DF_ / 64, BB / 64, 1), blk, 0, stream>>>(
        h1, Wf2, bf2, nullptr, h2, BB, DF_, DF_, 0, 0, 0, 1.0f);
    rul_kernel<<<BB, blk, 0, stream>>>(h2, Wf3, bf3, out);
}

// Round 19
// 1451.028 us; speedup vs baseline: 1.0840x; 1.0183x over previous
//
#include <hip/hip_runtime.h>
#include <hip/hip_bf16.h>
#include <math.h>

// ---------------------------------------------------------------------------
// Problem constants
// ---------------------------------------------------------------------------
#define BB   128     // batch
#define TT   1024    // time
#define CC_  512     // channels / variates (N)
#define DD   1024    // model dim
#define DF_  2048    // fc hidden
#define HH   64      // pool hidden
#define INV_SQRT_D 0.03125f   // 1/sqrt(1024)

typedef _Float16 f16;
typedef __attribute__((ext_vector_type(8))) _Float16 f16x8;
typedef __attribute__((ext_vector_type(4))) _Float16 f16x4;
typedef __attribute__((ext_vector_type(2))) _Float16 f16x2;
typedef __attribute__((ext_vector_type(4))) float f32x4;

__device__ __forceinline__ void gload_lds16(const void* g, void* l) {
    // async global->LDS, 16B per lane; LDS dest = wave-uniform base + lane*16
    __builtin_amdgcn_global_load_lds(
        (const __attribute__((address_space(1))) void*)g,
        (__attribute__((address_space(3))) void*)l, 16, 0, 0);
}

// Tile-packed operand layout (half-element index).  For a GEMM operand with
// row dim r (tiles of 128) and contraction dim k (tiles of 32, sub-chunks
// of 8): element (r,k) lives at
//   ((r>>7)*(K>>5) + (k>>5))*4096 + ((k>>3)&3)*1024 + (r&127)*8 + (k&7)
__device__ __forceinline__ long long paddr(long long r, int k, int K) {
    return ((r >> 7) * (long long)(K >> 5) + (k >> 5)) * 4096LL
         + (long long)(((k >> 3) & 3) * 1024 + ((int)(r & 127)) * 8 + (k & 7));
}

// ---------------------------------------------------------------------------
// fp16 MFMA GEMM (fp32 accumulate), 128x128 tile, BK=64, 4 waves,
// single-buffered 2-barrier loop, PACKED operands.
//   C[m,n] = act(alpha*sum_k A[m,k]*B[n,k] + add_c + bias[n])
//   OUT: 0 = fp32 C[M][N] row-major;  1 = packed f16 (r=m, k=n, K=N);
//        2 = packed f16 transposed (r=n, k=m, K=M)
//   ACT: 0 = none, 2 = exact gelu
// M,N multiples of 128; K multiple of 64.
// ---------------------------------------------------------------------------
template <int OUT, int ACT = 0>
__global__ __launch_bounds__(256, 4) void mfma_gemm(
    const f16* __restrict__ A, const f16* __restrict__ B,
    const float* __restrict__ bias, const float* __restrict__ add_c,
    void* __restrict__ C0,
    int M, int N, int K,
    long long sA, long long sB, long long sC, float alpha)
{
    // ---- XCD swizzle on flattened (x,y); identity when nwg % 8 != 0 ----
    const int gx = gridDim.x;
    const int nwg = gx * gridDim.y;
    int lin = blockIdx.y * gx + blockIdx.x;
    if ((nwg & 7) == 0) {
        const int cpx = nwg >> 3;
        lin = (lin & 7) * cpx + (lin >> 3);
    }
    const int bx = lin % gx, by = lin / gx;

    const int bz   = blockIdx.z;
    const int t    = threadIdx.x;
    const int wave = t >> 6, lane = t & 63;
    const int m0 = by * 128, n0 = bx * 128;
    const int wm = (wave >> 1) * 64, wn = (wave & 1) * 64;

    __shared__ __align__(16) f16 As[2][4096];   // 8 KB per sub-tile
    __shared__ __align__(16) f16 Bs[2][4096];

    f32x4 acc[4][4] = {};

    const int wbyte = wave * 1024;               // wave-uniform LDS base
    const long long tA = (long long)bz * sA + (long long)(m0 >> 7) * (K >> 5) * 4096;
    const long long tB = (long long)bz * sB + (long long)(n0 >> 7) * (K >> 5) * 4096;
    const f16* pA = A + tA + t * 8;
    const f16* pB = B + tB + t * 8;

    const int q   = lane >> 4;   // k-chunk for fragment reads
    const int r16 = lane & 15;

    for (int k0 = 0; k0 < K; k0 += 64) {
        const long long ko = (long long)(k0 >> 5) * 4096;
        __syncthreads();                       // previous compute done
        gload_lds16(pA + ko,        (char*)(&As[0][0]) + wbyte);
        gload_lds16(pA + ko + 2048, (char*)(&As[0][0]) + wbyte + 4096);
        gload_lds16(pA + ko + 4096, (char*)(&As[1][0]) + wbyte);
        gload_lds16(pA + ko + 6144, (char*)(&As[1][0]) + wbyte + 4096);
        gload_lds16(pB + ko,        (char*)(&Bs[0][0]) + wbyte);
        gload_lds16(pB + ko + 2048, (char*)(&Bs[0][0]) + wbyte + 4096);
        gload_lds16(pB + ko + 4096, (char*)(&Bs[1][0]) + wbyte);
        gload_lds16(pB + ko + 6144, (char*)(&Bs[1][0]) + wbyte + 4096);
        __syncthreads();                       // drains vmcnt: tiles ready

        #pragma unroll
        for (int s = 0; s < 2; ++s) {
            const f16x8* AV = (const f16x8*)(&As[s][0]);
            const f16x8* BV = (const f16x8*)(&Bs[s][0]);
            f16x8 bfr[4];
            #pragma unroll
            for (int j = 0; j < 4; ++j)
                bfr[j] = BV[q * 128 + wn + j * 16 + r16];
            __builtin_amdgcn_s_setprio(1);
            #pragma unroll
            for (int i = 0; i < 4; ++i) {
                const f16x8 a = AV[q * 128 + wm + i * 16 + r16];
                #pragma unroll
                for (int j = 0; j < 4; ++j)
                    acc[i][j] = __builtin_amdgcn_mfma_f32_16x16x32_f16(
                        a, bfr[j], acc[i][j], 0, 0, 0);
            }
            __builtin_amdgcn_s_setprio(0);
        }
    }

    // epilogue: C/D layout col = lane&15, row = (lane>>4)*4 + r
    const float cadd = add_c ? add_c[0] : 0.0f;
    const int col = lane & 15;
    const int rb  = (lane >> 4) * 4;
    #pragma unroll
    for (int j = 0; j < 4; ++j) {
        const int n = n0 + wn + j * 16 + col;
        const float bv = bias ? bias[n] : 0.0f;
        #pragma unroll
        for (int i = 0; i < 4; ++i) {
            const int m = m0 + wm + i * 16 + rb;
            f32x4 v = acc[i][j];
            #pragma unroll
            for (int r = 0; r < 4; ++r) {
                v[r] = v[r] * alpha + cadd + bv;
                if constexpr (ACT == 2)
                    v[r] = 0.5f * v[r] * (1.0f + erff(v[r] * 0.70710678118654752f));
            }
            if constexpr (OUT == 0) {
                float* C = (float*)C0 + (long long)bz * sC;
                #pragma unroll
                for (int r = 0; r < 4; ++r) C[(long long)(m + r) * N + n] = v[r];
            } else if constexpr (OUT == 1) {
                // packed: (r=m+r, k=n), K=N
                f16* C = (f16*)C0 + (long long)bz * sC;
                #pragma unroll
                for (int r = 0; r < 4; ++r)
                    C[paddr(m + r, n, N)] = (f16)v[r];
            } else {
                // packed transposed: (r=n, k=m..m+3), K=M;  m%8 in {0,4}
                f16* C = (f16*)C0 + (long long)bz * sC;
                f16 p[4];
                #pragma unroll
                for (int r = 0; r < 4; ++r) p[r] = (f16)v[r];
                *reinterpret_cast<f16x4*>(&C[paddr(n, m, M)]) =
                    *reinterpret_cast<f16x4*>(p);
            }
        }
    }
}

// ---------------------------------------------------------------------------
// fp32 [R][Cc] -> packed fp16 (rows = Cc-dim, k = original row dim, len R).
// value for output (row c0+c, k r0+8q+j) = tile[8q+j][c].
// ---------------------------------------------------------------------------
__global__ __launch_bounds__(256) void transpose_h_kernel(
    const float* __restrict__ in, f16* __restrict__ o,
    int R, int Cc, long long sIn, long long sOut)
{
    const int b = blockIdx.z;
    in += (long long)b * sIn; o += (long long)b * sOut;
    __shared__ float tile[32][33];
    const int c0 = blockIdx.x * 32, r0 = blockIdx.y * 32;
    const int tx = threadIdx.x & 31, ty = threadIdx.x >> 5;   // 32 x 8
    #pragma unroll
    for (int i = 0; i < 32; i += 8)
        tile[ty + i][tx] = in[(long long)(r0 + ty + i) * Cc + (c0 + tx)];
    __syncthreads();
    if (threadIdx.x < 128) {
        const int c = threadIdx.x & 31, q = threadIdx.x >> 5;
        f16 p[8];
        #pragma unroll
        for (int j = 0; j < 8; ++j) p[j] = (f16)tile[8 * q + j][c];
        const long long base =
            (((long long)(c0 + c) >> 7) * (long long)(R >> 5) + (r0 >> 5)) * 4096LL
            + q * 1024 + ((c0 + c) & 127) * 8;
        *reinterpret_cast<f16x8*>(&o[base]) = *reinterpret_cast<f16x8*>(p);
    }
}

// fp32 [R][1024] -> packed fp16 (K=1024), row-major pack (no transpose)
__global__ __launch_bounds__(256) void cvt_h_kernel(
    const float* __restrict__ in, f16* __restrict__ o, long long n)
{
    const long long i = ((long long)blockIdx.x * 256 + threadIdx.x) * 4;
    if (i >= n) return;
    const float4 v = *reinterpret_cast<const float4*>(in + i);
    f16 p[4] = {(f16)v.x, (f16)v.y, (f16)v.z, (f16)v.w};
    const long long r = i >> 10;
    const int k = (int)(i & 1023);
    *reinterpret_cast<f16x4*>(&o[paddr(r, k, 1024)]) = *reinterpret_cast<f16x4*>(p);
}

// zero-fill f16 buffer (n halves, multiple of 2048)
__global__ __launch_bounds__(256) void zero_h_kernel(f16* __restrict__ p, long long n)
{
    const long long i = ((long long)blockIdx.x * 256 + threadIdx.x) * 8;
    if (i >= n) return;
    f16x8 z = {};
    *reinterpret_cast<f16x8*>(p + i) = z;
}

// bias pad: out[0..63]=in, out[64..127]=0
__global__ __launch_bounds__(128) void pad_bias_kernel(
    const float* __restrict__ in, float* __restrict__ o)
{
    const int i = threadIdx.x;
    o[i] = (i < HH) ? in[i] : 0.0f;
}

// out[r] = scale * dot(W[r, 0:1024], v[0:1024]);  one wave per row
__global__ __launch_bounds__(256) void rowdot_kernel(
    const float* __restrict__ W, const float* __restrict__ v,
    float* __restrict__ out, float scale)
{
    const int row  = blockIdx.x * 4 + (threadIdx.x >> 6);
    const int lane = threadIdx.x & 63;
    const float* wr = W + (long long)row * 1024;
    float s = 0.0f;
    for (int k = lane; k < 1024; k += 64) s += wr[k] * v[k];
    #pragma unroll
    for (int off = 32; off; off >>= 1) s += __shfl_down(s, off);
    if (lane == 0) out[row] = s * scale;
}

// ---------------------------------------------------------------------------
// Single-pass LayerNorm over K=1024 on PACKED f16, in place, register-resident.
// Block = 32 rows (quarter of a 128-row group); 8 threads per row; each
// thread holds 16 f16x8 chunks (its row's k in [s*128, s*128+128)).
// Chunk c = s*16+i -> tile = c>>2, q = c&3, kbase = 8c.
// ---------------------------------------------------------------------------
__global__ __launch_bounds__(256) void layernorm_pr_kernel(
    f16* __restrict__ x, const float* __restrict__ g, const float* __restrict__ b)
{
    const int grp = blockIdx.x >> 2;     // 128-row group
    const int qr  = blockIdx.x & 3;      // quarter: rows qr*32..+31
    f16* base = x + (long long)grp * 131072 + (qr * 32) * 8;
    const int t = threadIdx.x;
    const int r = t & 31;                // row within quarter
    const int s = t >> 5;                // 0..7 k-slice

    __shared__ float gs[1024], bs[1024];
    __shared__ float ssum[256], ssq[256];

    f16x8 vbuf[16];
    float sum = 0.0f, sq = 0.0f;
    #pragma unroll
    for (int i = 0; i < 16; ++i) {
        const int c = s * 16 + i;
        const int tile = c >> 2, q = c & 3;
        vbuf[i] = *reinterpret_cast<const f16x8*>(
            base + tile * 4096 + q * 1024 + r * 8);
        #pragma unroll
        for (int j = 0; j < 8; ++j) {
            const float f = (float)vbuf[i][j];
            sum += f; sq += f * f;
        }
    }
    for (int i = t; i < 1024; i += 256) { gs[i] = g[i]; bs[i] = b[i]; }
    ssum[t] = sum; ssq[t] = sq;
    __syncthreads();
    float rsum = 0.0f, rsq = 0.0f;
    #pragma unroll
    for (int ss = 0; ss < 8; ++ss) {
        rsum += ssum[ss * 32 + r];
        rsq  += ssq[ss * 32 + r];
    }
    const float mean = rsum * (1.0f / DD);
    const float var  = rsq * (1.0f / DD) - mean * mean;
    const float rstd = rsqrtf(fmaxf(var, 0.0f) + 1e-5f);

    #pragma unroll
    for (int i = 0; i < 16; ++i) {
        const int c = s * 16 + i;
        const int tile = c >> 2, q = c & 3;
        const int kbase = c * 8;
        f16 o[8];
        #pragma unroll
        for (int j = 0; j < 8; ++j)
            o[j] = (f16)(((float)vbuf[i][j] - mean) * rstd * gs[kbase + j]
                         + bs[kbase + j]);
        *reinterpret_cast<f16x8*>(base + tile * 4096 + q * 1024 + r * 8) =
            *reinterpret_cast<f16x8*>(o);
    }
}

// ---------------------------------------------------------------------------
// Row softmax over 512 cols, fp32 in -> packed fp16 (K=512)
// ---------------------------------------------------------------------------
__global__ __launch_bounds__(256) void softmax512_h_kernel(
    const float* __restrict__ x, f16* __restrict__ o)
{
    const long long row = blockIdx.x;
    const float2 v = reinterpret_cast<const float2*>(x + row * 512)[threadIdx.x];
    const int t = threadIdx.x;

    __shared__ float red[4];
    float mx = fmaxf(v.x, v.y);
    #pragma unroll
    for (int off = 32; off; off >>= 1) mx = fmaxf(mx, __shfl_down(mx, off));
    if ((t & 63) == 0) red[t >> 6] = mx;
    __syncthreads();
    mx = fmaxf(fmaxf(red[0], red[1]), fmaxf(red[2], red[3]));
    __syncthreads();

    const float e0 = expf(v.x - mx), e1 = expf(v.y - mx);
    float s = e0 + e1;
    #pragma unroll
    for (int off = 32; off; off >>= 1) s += __shfl_down(s, off);
    if ((t & 63) == 0) red[t >> 6] = s;
    __syncthreads();
    s = red[0] + red[1] + red[2] + red[3];
    const float inv = 1.0f / s;

    f16 p[2] = {(f16)(e0 * inv), (f16)(e1 * inv)};
    *reinterpret_cast<f16x2*>(&o[paddr(row, 2 * t, 512)]) =
        *reinterpret_cast<f16x2*>(p);
}

// fp32 row softmax over 512 in place (pool weights)
__global__ __launch_bounds__(256) void softmax512_kernel(float* __restrict__ x)
{
    const long long row = blockIdx.x;
    float2* xr = reinterpret_cast<float2*>(x + row * 512);
    const int t = threadIdx.x;
    float2 v = xr[t];

    __shared__ float red[4];
    float mx = fmaxf(v.x, v.y);
    #pragma unroll
    for (int off = 32; off; off >>= 1) mx = fmaxf(mx, __shfl_down(mx, off));
    if ((t & 63) == 0) red[t >> 6] = mx;
    __syncthreads();
    mx = fmaxf(fmaxf(red[0], red[1]), fmaxf(red[2], red[3]));
    __syncthreads();

    const float e0 = expf(v.x - mx), e1 = expf(v.y - mx);
    float s = e0 + e1;
    #pragma unroll
    for (int off = 32; off; off >>= 1) s += __shfl_down(s, off);
    if ((t & 63) == 0) red[t >> 6] = s;
    __syncthreads();
    s = red[0] + red[1] + red[2] + red[3];
    const float inv = 1.0f / s;
    xr[t] = make_float2(e0 * inv, e1 * inv);
}

// ---------------------------------------------------------------------------
// fp32 tiled GEMM (kept for the small fc head ops)
// ---------------------------------------------------------------------------
#define BM 64
#define BN 64
#define BK 16

template <int TA, int TB, int ACT>
__global__ __launch_bounds__(256) void gemm_kernel(
    const float* __restrict__ A, const float* __restrict__ B,
    const float* __restrict__ bias, const float* __restrict__ add_const_ptr,
    float* __restrict__ C,
    int M, int N, int K,
    long long strideA, long long strideB, long long strideC,
    float alpha)
{
    const int batch = blockIdx.z;
    A += (long long)batch * strideA;
    B += (long long)batch * strideB;
    C += (long long)batch * strideC;

    __shared__ float As[BK][BM + 4];
    __shared__ float Bs[BK][BN + 4];

    const int t  = threadIdx.x;
    const int tx = t & 15;
    const int ty = t >> 4;
    const int m0 = blockIdx.y * BM;
    const int n0 = blockIdx.x * BN;

    float acc[4][4] = {};

    for (int k0 = 0; k0 < K; k0 += BK) {
        if (TA == 0) {
            const int mm = t >> 2;
            const int kk = (t & 3) * 4;
            const float4 v = *reinterpret_cast<const float4*>(
                &A[(long long)(m0 + mm) * K + (k0 + kk)]);
            As[kk + 0][mm] = v.x; As[kk + 1][mm] = v.y;
            As[kk + 2][mm] = v.z; As[kk + 3][mm] = v.w;
        } else {
            const int kk = t >> 4;
            const int mm = (t & 15) * 4;
            const float4 v = *reinterpret_cast<const float4*>(
                &A[(long long)(k0 + kk) * M + (m0 + mm)]);
            *reinterpret_cast<float4*>(&As[kk][mm]) = v;
        }
        if (TB == 0) {
            const int kk = t >> 4;
            const int nn = (t & 15) * 4;
            const float4 v = *reinterpret_cast<const float4*>(
                &B[(long long)(k0 + kk) * N + (n0 + nn)]);
            *reinterpret_cast<float4*>(&Bs[kk][nn]) = v;
        } else {
            const int nn = t >> 2;
            const int kk = (t & 3) * 4;
            const float4 v = *reinterpret_cast<const float4*>(
                &B[(long long)(n0 + nn) * K + (k0 + kk)]);
            Bs[kk + 0][nn] = v.x; Bs[kk + 1][nn] = v.y;
            Bs[kk + 2][nn] = v.z; Bs[kk + 3][nn] = v.w;
        }
        __syncthreads();

        #pragma unroll
        for (int kk = 0; kk < BK; ++kk) {
            float a[4], b[4];
            #pragma unroll
            for (int i = 0; i < 4; ++i) a[i] = As[kk][ty * 4 + i];
            #pragma unroll
            for (int j = 0; j < 4; ++j) b[j] = Bs[kk][tx * 4 + j];
            #pragma unroll
            for (int i = 0; i < 4; ++i)
                #pragma unroll
                for (int j = 0; j < 4; ++j)
                    acc[i][j] = fmaf(a[i], b[j], acc[i][j]);
        }
        __syncthreads();
    }

    const float cadd = add_const_ptr ? add_const_ptr[0] : 0.0f;
    #pragma unroll
    for (int i = 0; i < 4; ++i) {
        const int m = m0 + ty * 4 + i;
        #pragma unroll
        for (int j = 0; j < 4; ++j) {
            const int n = n0 + tx * 4 + j;
            float v = acc[i][j] * alpha + cadd;
            if (bias) v += bias[n];
            if (ACT == 1) v = (v > 0.0f) ? v : 0.01f * v;
            else if (ACT == 2) v = 0.5f * v * (1.0f + erff(v * 0.70710678118654752f));
            C[(long long)m * N + n] = v;
        }
    }
}

// pool_scores[row] = h[row,:64] . Wp2 + bp2   (h row stride = 128)
__global__ __launch_bounds__(256) void pool_score_kernel(
    const float* __restrict__ h, const float* __restrict__ Wp2,
    const float* __restrict__ bp2, float* __restrict__ out)
{
    const int row  = blockIdx.x * 4 + (threadIdx.x >> 6);
    const int lane = threadIdx.x & 63;
    float v = h[(long long)row * 128 + lane] * Wp2[lane];
    #pragma unroll
    for (int off = 32; off; off >>= 1) v += __shfl_down(v, off);
    if (lane == 0) out[row] = v + bp2[0];
}

// pooled[b,d] = sum_n fused[b,n,d] * w[b,n]   (fused = packed f16, K=1024)
__global__ __launch_bounds__(256) void pooled_kernel(
    const f16* __restrict__ fused, const float* __restrict__ w,
    float* __restrict__ out)
{
    const int b = blockIdx.y;
    const int d = blockIdx.x * 256 + threadIdx.x;
    __shared__ float ws_[CC_];
    for (int i = threadIdx.x; i < CC_; i += 256) ws_[i] = w[(long long)b * CC_ + i];
    __syncthreads();
    const long long dpart = (long long)(d >> 5) * 4096
                          + ((d >> 3) & 3) * 1024 + (d & 7);
    float acc = 0.0f;
    for (int n = 0; n < CC_; ++n) {
        const long long r = (long long)b * CC_ + n;
        const long long addr = ((r >> 7) * 32) * 4096 + dpart + (r & 127) * 8;
        acc = fmaf((float)fused[addr], ws_[n], acc);
    }
    out[(long long)b * DD + d] = acc;
}

// rul[b] = |h2[b,:] . Wf3 + bf3|
__global__ __launch_bounds__(256) void rul_kernel(
    const float* __restrict__ h2, const float* __restrict__ Wf3,
    const float* __restrict__ bf3, float* __restrict__ out)
{
    const int b = blockIdx.x;
    const int t = threadIdx.x;
    float acc = 0.0f;
    for (int k = t; k < DF_; k += 256)
        acc = fmaf(h2[(long long)b * DF_ + k], Wf3[k], acc);
    __shared__ float red[4];
    #pragma unroll
    for (int off = 32; off; off >>= 1) acc += __shfl_down(acc, off);
    if ((t & 63) == 0) red[t >> 6] = acc;
    __syncthreads();
    if (t == 0) out[b] = fabsf(red[0] + red[1] + red[2] + red[3] + bf3[0]);
}

// ---------------------------------------------------------------------------
// Launch
// ---------------------------------------------------------------------------
extern "C" void kernel_launch(void* const* d_in, const int* in_sizes, int n_in,
                              void* d_out, int out_size, void* d_ws, size_t ws_size,
                              hipStream_t stream)
{
    const float* x_enc   = (const float*)d_in[0];
    const float* W_emb   = (const float*)d_in[2];
    const float* b_emb   = (const float*)d_in[3];
    const float* g_s     = (const float*)d_in[4];
    const float* b_s     = (const float*)d_in[5];
    const float* basis   = (const float*)d_in[6];
    const float* Wq      = (const float*)d_in[7];
    const float* bq      = (const float*)d_in[8];
    const float* Wk      = (const float*)d_in[9];
    // bk (d_in[10]) and age_scale (d_in[13]) drop out of softmax (per-row consts)
    const float* Wv      = (const float*)d_in[11];
    const float* bv      = (const float*)d_in[12];
    const float* g_f     = (const float*)d_in[14];
    const float* b_f     = (const float*)d_in[15];
    const float* Wp1     = (const float*)d_in[16];
    const float* bp1     = (const float*)d_in[17];
    const float* Wp2     = (const float*)d_in[18];
    const float* bp2     = (const float*)d_in[19];
    const float* Wf1     = (const float*)d_in[20];
    const float* bf1     = (const float*)d_in[21];
    const float* Wf2     = (const float*)d_in[22];
    const float* bf2     = (const float*)d_in[23];
    const float* Wf3     = (const float*)d_in[24];
    const float* bf3     = (const float*)d_in[25];
    float* out = (float*)d_out;
    (void)in_sizes; (void)n_in; (void)out_size; (void)ws_size;

    // ---- workspace layout (MB offsets, liveness-reused; peak < 896 MB) ----
    const unsigned long long MBy = 1048576ULL;
    char* ws = (char*)d_ws;
    f16*  xT     = (f16*)(ws + 0 * MBy);       // packed [B] r=C,K=T (dead after sensor)
    f16*  WembT  = (f16*)(ws + 128 * MBy);     // packed r=D,K=T   2 MB
    f16*  Wqc    = (f16*)(ws + 130 * MBy);     // packed r=e(in),K=o  2 MB
    f16*  Wkc    = (f16*)(ws + 132 * MBy);     // packed r=i(in),K=o  2 MB
    f16*  Pt     = (f16*)(ws + 134 * MBy);     // packed r=i,K=e   2 MB (Wq Wk^T)^T
    f16*  W2t    = (f16*)(ws + 136 * MBy);     // packed r=m,K=e   1 MB (Wq bas^T)^T
    f16*  bas    = (f16*)(ws + 137 * MBy);     // packed r=C,K=D   1 MB
    f16*  Wp1p   = (f16*)(ws + 138 * MBy);     // packed r=128(pad),K=D
    float* bp1p  = (float*)(ws + 139 * MBy);   // padded bias [128]
    float* pbias = (float*)(ws + 139 * MBy + 4096);   // [1024]
    float* c2s   = (float*)(ws + 139 * MBy + 16384);  // [512]
    f16*  WvT    = (f16*)(ws + 140 * MBy);     // packed r=D,K=D   2 MB
    f16*  sens   = (f16*)(ws + 256 * MBy);     // packed r=BC,K=D  (LN in place)
    f16*  QWp    = (f16*)(ws + 0 * MBy);       // packed r=BC,K=D (xT dead) 128 MB
    f16*  T1     = (f16*)(ws + 512 * MBy);     // packed [B] r=C,K=C  64 MB
    f16*  S2T    = (f16*)(ws + 640 * MBy);     // packed [B] r=C,K=C  64 MB
    float* S3    = (float*)(ws + 704 * MBy);   // [B][C][C] fp32  128 MB
    f16*  attn   = (f16*)(ws + 0 * MBy);       // packed r=BC,K=C (QWp dead)
    f16*  VT     = (f16*)(ws + 384 * MBy);     // packed [B] r=D,K=C  128 MB
    f16*  fusedp = (f16*)(ws + 512 * MBy);     // packed r=BC,K=D (T1/S2T dead)
    float* hpool = (float*)(ws + 704 * MBy);   // [BC][128] fp32 (S3 dead)
    float* pscr  = (float*)(ws + 840 * MBy);
    float* pooled= (float*)(ws + 842 * MBy);
    float* h1    = (float*)(ws + 844 * MBy);
    float* h2    = (float*)(ws + 848 * MBy);

    const long long CD  = (long long)CC_ * DD;   // 524288
    const long long CCs = (long long)CC_ * CC_;  // 262144
    const long long DC  = (long long)DD * CC_;
    const dim3 blk(256);

    // ---- upfront prep ----
    transpose_h_kernel<<<dim3(CC_ / 32, TT / 32, BB), blk, 0, stream>>>(
        x_enc, xT, TT, CC_, (long long)TT * CC_, (long long)CC_ * TT);
    transpose_h_kernel<<<dim3(DD / 32, TT / 32, 1), blk, 0, stream>>>(
        W_emb, WembT, TT, DD, 0, 0);
    transpose_h_kernel<<<dim3(DD / 32, DD / 32, 1), blk, 0, stream>>>(
        Wv, WvT, DD, DD, 0, 0);
    cvt_h_kernel<<<(DD * DD) / 1024, blk, 0, stream>>>(Wq, Wqc, (long long)DD * DD);
    cvt_h_kernel<<<(DD * DD) / 1024, blk, 0, stream>>>(Wk, Wkc, (long long)DD * DD);
    cvt_h_kernel<<<(CC_ * DD) / 1024, blk, 0, stream>>>(
        basis, bas, (long long)CC_ * DD);
    zero_h_kernel<<<64, blk, 0, stream>>>(Wp1p, 131072);
    transpose_h_kernel<<<dim3(HH / 32, DD / 32, 1), blk, 0, stream>>>(
        Wp1, Wp1p, DD, HH, 0, 0);
    pad_bias_kernel<<<1, 128, 0, stream>>>(bp1, bp1p);
    // pbias[i] = Wk[i,:] . bq ;  c2s[m] = s * (basis[m,:] . bq)
    rowdot_kernel<<<DD / 4, blk, 0, stream>>>(Wk, bq, pbias, 1.0f);
    rowdot_kernel<<<CC_ / 4, blk, 0, stream>>>(basis, bq, c2s, INV_SQRT_D);
    // P^T: P[e,i] = sum_o Wq[e,o] Wk[i,o]; OUT=2 -> packed(r=i, k=e)
    mfma_gemm<2><<<dim3(DD / 128, DD / 128, 1), blk, 0, stream>>>(
        Wqc, Wkc, nullptr, nullptr, Pt, DD, DD, DD, 0, 0, 0, 1.0f);
    // W2^T: W2[e,m] = sum_o Wq[e,o] bas[m,o]; OUT=2 -> packed(r=m, k=e)
    mfma_gemm<2><<<dim3(CC_ / 128, DD / 128, 1), blk, 0, stream>>>(
        Wqc, bas, nullptr, nullptr, W2t, DD, CC_, DD, 0, 0, 0, 1.0f);

    // ---- main pipeline ----
    // sensor = xT @ WembT^T + b_emb -> packed f16
    mfma_gemm<1><<<dim3(DD / 128, CC_ / 128, BB), blk, 0, stream>>>(
        xT, WembT, b_emb, nullptr, sens,
        CC_, DD, TT, (long long)CC_ * TT, 0, CD, 1.0f);
    layernorm_pr_kernel<<<(BB * CC_) / 32, blk, 0, stream>>>(sens, g_s, b_s);
    // QW = sens @ P + pbias -> packed (r=BC, K=D)   [= Q Wk^T exactly]
    mfma_gemm<1><<<dim3(DD / 128, (BB * CC_) / 128, 1), blk, 0, stream>>>(
        sens, Pt, pbias, nullptr, QWp,
        BB * CC_, DD, DD, 0, 0, 0, 1.0f);
    // S2T = (s*(sens @ W2) + s*c2)^T packed (rows m, K=C) per batch [= age_bias^T]
    mfma_gemm<2><<<dim3(CC_ / 128, CC_ / 128, BB), blk, 0, stream>>>(
        sens, W2t, c2s, nullptr, S2T,
        CC_, CC_, DD, CD, 0, CCs, INV_SQRT_D);
    // T1 = (s * QW @ sens^T)^T packed (rows k, K=C) per batch
    mfma_gemm<2><<<dim3(CC_ / 128, CC_ / 128, BB), blk, 0, stream>>>(
        QWp, sens, nullptr, nullptr, T1,
        CC_, CC_, DD, CD, CD, CCs, INV_SQRT_D);
    // S3[n,k] = sum_j S2T[n,j]*T1[k,j]   (fp32 out)
    mfma_gemm<0><<<dim3(CC_ / 128, CC_ / 128, BB), blk, 0, stream>>>(
        S2T, T1, nullptr, nullptr, S3,
        CC_, CC_, CC_, CCs, CCs, CCs, 1.0f);
    // attn = softmax(S3) -> packed fp16 (rows flat BC, K=C)
    softmax512_h_kernel<<<BB * CC_, blk, 0, stream>>>(S3, attn);
    // VT = (sensor @ Wv + bv)^T packed (rows D, K=C) per batch
    mfma_gemm<2><<<dim3(DD / 128, CC_ / 128, BB), blk, 0, stream>>>(
        sens, WvT, bv, nullptr, VT,
        CC_, DD, DD, CD, 0, DC, 1.0f);
    // fused = attn @ VT^T / 32 -> packed f16 (rows flat BC, K=D)
    mfma_gemm<1><<<dim3(DD / 128, CC_ / 128, BB), blk, 0, stream>>>(
        attn, VT, nullptr, nullptr, fusedp,
        CC_, DD, CC_, CCs, DC, CD, INV_SQRT_D);
    layernorm_pr_kernel<<<(BB * CC_) / 32, blk, 0, stream>>>(fusedp, g_f, b_f);
    // hpool = gelu(fused @ Wp1 + bp1)  (MFMA, padded N=128)
    mfma_gemm<0, 2><<<dim3(1, (BB * CC_) / 128, 1), blk, 0, stream>>>(
        fusedp, Wp1p, bp1p, nullptr, hpool,
        BB * CC_, 128, DD, 0, 0, 0, 1.0f);
    // pool scores + softmax over C
    pool_score_kernel<<<(BB * CC_) / 4, blk, 0, stream>>>(hpool, Wp2, bp2, pscr);
    softmax512_kernel<<<BB, blk, 0, stream>>>(pscr);
    // pooled (reads packed fused)
    pooled_kernel<<<dim3(DD / 256, BB), blk, 0, stream>>>(fusedp, pscr, pooled);
    // fc head
    gemm_kernel<0, 0, 1><<<dim3(DF_ / 64, BB / 64, 1), blk, 0, stream>>>(
        pooled, Wf1, bf1, nullptr, h1, BB, DF_, DD, 0, 0, 0, 1.0f);
    gemm_kernel<0, 0, 0><<<dim3(DF_ / 64, BB / 64, 1), blk, 0, stream>>>(
        h1, Wf2, bf2, nullptr, h2, BB, DF_, DF_, 0, 0, 0, 1.0f);
    rul_kernel<<<BB, blk, 0, stream>>>(h2, Wf3, bf3, out);
}

// Round 20
// 1323.007 us; speedup vs baseline: 1.1889x; 1.0968x over previous
//
#include <hip/hip_runtime.h>
#include <hip/hip_bf16.h>
#include <math.h>

// ---------------------------------------------------------------------------
// Problem constants
// ---------------------------------------------------------------------------
#define BB   128     // batch
#define TT   1024    // time
#define CC_  512     // channels / variates (N)
#define DD   1024    // model dim
#define DF_  2048    // fc hidden
#define HH   64      // pool hidden
#define INV_SQRT_D 0.03125f   // 1/sqrt(1024)

typedef _Float16 f16;
typedef __attribute__((ext_vector_type(8))) _Float16 f16x8;
typedef __attribute__((ext_vector_type(4))) _Float16 f16x4;
typedef __attribute__((ext_vector_type(2))) _Float16 f16x2;
typedef __attribute__((ext_vector_type(4))) float f32x4;

__device__ __forceinline__ void gload_lds16(const void* g, void* l) {
    // async global->LDS, 16B per lane; LDS dest = wave-uniform base + lane*16
    __builtin_amdgcn_global_load_lds(
        (const __attribute__((address_space(1))) void*)g,
        (__attribute__((address_space(3))) void*)l, 16, 0, 0);
}

// Tile-packed operand layout (half-element index).  For a GEMM operand with
// row dim r (tiles of 128) and contraction dim k (tiles of 32, sub-chunks
// of 8): element (r,k) lives at
//   ((r>>7)*(K>>5) + (k>>5))*4096 + ((k>>3)&3)*1024 + (r&127)*8 + (k&7)
__device__ __forceinline__ long long paddr(long long r, int k, int K) {
    return ((r >> 7) * (long long)(K >> 5) + (k >> 5)) * 4096LL
         + (long long)(((k >> 3) & 3) * 1024 + ((int)(r & 127)) * 8 + (k & 7));
}

// ---------------------------------------------------------------------------
// fp16 MFMA GEMM (fp32 accumulate), 128x128 tile, BK=64, 4 waves,
// single-buffered 2-barrier loop, PACKED operands.
//   C[m,n] = act(alpha*sum_k A[m,k]*B[n,k] + add_c + bias[n])
//   OUT: 0 = fp32 C[M][N] row-major;  1 = packed f16 (r=m, k=n, K=N);
//        2 = packed f16 transposed (r=n, k=m, K=M)
//   ACT: 0 = none, 1 = leaky_relu(0.01), 2 = exact gelu
// M,N multiples of 128; K multiple of 64.
// ---------------------------------------------------------------------------
template <int OUT, int ACT = 0>
__global__ __launch_bounds__(256, 4) void mfma_gemm(
    const f16* __restrict__ A, const f16* __restrict__ B,
    const float* __restrict__ bias, const float* __restrict__ add_c,
    void* __restrict__ C0,
    int M, int N, int K,
    long long sA, long long sB, long long sC, float alpha)
{
    // ---- XCD swizzle on flattened (x,y); identity when nwg % 8 != 0 ----
    const int gx = gridDim.x;
    const int nwg = gx * gridDim.y;
    int lin = blockIdx.y * gx + blockIdx.x;
    if ((nwg & 7) == 0) {
        const int cpx = nwg >> 3;
        lin = (lin & 7) * cpx + (lin >> 3);
    }
    const int bx = lin % gx, by = lin / gx;

    const int bz   = blockIdx.z;
    const int t    = threadIdx.x;
    const int wave = t >> 6, lane = t & 63;
    const int m0 = by * 128, n0 = bx * 128;
    const int wm = (wave >> 1) * 64, wn = (wave & 1) * 64;

    __shared__ __align__(16) f16 As[2][4096];   // 8 KB per sub-tile
    __shared__ __align__(16) f16 Bs[2][4096];

    f32x4 acc[4][4] = {};

    const int wbyte = wave * 1024;               // wave-uniform LDS base
    const long long tA = (long long)bz * sA + (long long)(m0 >> 7) * (K >> 5) * 4096;
    const long long tB = (long long)bz * sB + (long long)(n0 >> 7) * (K >> 5) * 4096;
    const f16* pA = A + tA + t * 8;
    const f16* pB = B + tB + t * 8;

    const int q   = lane >> 4;   // k-chunk for fragment reads
    const int r16 = lane & 15;

    for (int k0 = 0; k0 < K; k0 += 64) {
        const long long ko = (long long)(k0 >> 5) * 4096;
        __syncthreads();                       // previous compute done
        gload_lds16(pA + ko,        (char*)(&As[0][0]) + wbyte);
        gload_lds16(pA + ko + 2048, (char*)(&As[0][0]) + wbyte + 4096);
        gload_lds16(pA + ko + 4096, (char*)(&As[1][0]) + wbyte);
        gload_lds16(pA + ko + 6144, (char*)(&As[1][0]) + wbyte + 4096);
        gload_lds16(pB + ko,        (char*)(&Bs[0][0]) + wbyte);
        gload_lds16(pB + ko + 2048, (char*)(&Bs[0][0]) + wbyte + 4096);
        gload_lds16(pB + ko + 4096, (char*)(&Bs[1][0]) + wbyte);
        gload_lds16(pB + ko + 6144, (char*)(&Bs[1][0]) + wbyte + 4096);
        __syncthreads();                       // drains vmcnt: tiles ready

        #pragma unroll
        for (int s = 0; s < 2; ++s) {
            const f16x8* AV = (const f16x8*)(&As[s][0]);
            const f16x8* BV = (const f16x8*)(&Bs[s][0]);
            f16x8 bfr[4];
            #pragma unroll
            for (int j = 0; j < 4; ++j)
                bfr[j] = BV[q * 128 + wn + j * 16 + r16];
            __builtin_amdgcn_s_setprio(1);
            #pragma unroll
            for (int i = 0; i < 4; ++i) {
                const f16x8 a = AV[q * 128 + wm + i * 16 + r16];
                #pragma unroll
                for (int j = 0; j < 4; ++j)
                    acc[i][j] = __builtin_amdgcn_mfma_f32_16x16x32_f16(
                        a, bfr[j], acc[i][j], 0, 0, 0);
            }
            __builtin_amdgcn_s_setprio(0);
        }
    }

    // epilogue: C/D layout col = lane&15, row = (lane>>4)*4 + r
    const float cadd = add_c ? add_c[0] : 0.0f;
    const int col = lane & 15;
    const int rb  = (lane >> 4) * 4;
    #pragma unroll
    for (int j = 0; j < 4; ++j) {
        const int n = n0 + wn + j * 16 + col;
        const float bv = bias ? bias[n] : 0.0f;
        #pragma unroll
        for (int i = 0; i < 4; ++i) {
            const int m = m0 + wm + i * 16 + rb;
            f32x4 v = acc[i][j];
            #pragma unroll
            for (int r = 0; r < 4; ++r) {
                v[r] = v[r] * alpha + cadd + bv;
                if constexpr (ACT == 1)
                    v[r] = (v[r] > 0.0f) ? v[r] : 0.01f * v[r];
                else if constexpr (ACT == 2)
                    v[r] = 0.5f * v[r] * (1.0f + erff(v[r] * 0.70710678118654752f));
            }
            if constexpr (OUT == 0) {
                float* C = (float*)C0 + (long long)bz * sC;
                #pragma unroll
                for (int r = 0; r < 4; ++r) C[(long long)(m + r) * N + n] = v[r];
            } else if constexpr (OUT == 1) {
                // packed: (r=m+r, k=n), K=N
                f16* C = (f16*)C0 + (long long)bz * sC;
                #pragma unroll
                for (int r = 0; r < 4; ++r)
                    C[paddr(m + r, n, N)] = (f16)v[r];
            } else {
                // packed transposed: (r=n, k=m..m+3), K=M;  m%8 in {0,4}
                f16* C = (f16*)C0 + (long long)bz * sC;
                f16 p[4];
                #pragma unroll
                for (int r = 0; r < 4; ++r) p[r] = (f16)v[r];
                *reinterpret_cast<f16x4*>(&C[paddr(n, m, M)]) =
                    *reinterpret_cast<f16x4*>(p);
            }
        }
    }
}

// ---------------------------------------------------------------------------
// fp32 [R][Cc] -> packed fp16 (rows = Cc-dim, k = original row dim, len R).
// value for output (row c0+c, k r0+8q+j) = tile[8q+j][c].
// ---------------------------------------------------------------------------
__global__ __launch_bounds__(256) void transpose_h_kernel(
    const float* __restrict__ in, f16* __restrict__ o,
    int R, int Cc, long long sIn, long long sOut)
{
    const int b = blockIdx.z;
    in += (long long)b * sIn; o += (long long)b * sOut;
    __shared__ float tile[32][33];
    const int c0 = blockIdx.x * 32, r0 = blockIdx.y * 32;
    const int tx = threadIdx.x & 31, ty = threadIdx.x >> 5;   // 32 x 8
    #pragma unroll
    for (int i = 0; i < 32; i += 8)
        tile[ty + i][tx] = in[(long long)(r0 + ty + i) * Cc + (c0 + tx)];
    __syncthreads();
    if (threadIdx.x < 128) {
        const int c = threadIdx.x & 31, q = threadIdx.x >> 5;
        f16 p[8];
        #pragma unroll
        for (int j = 0; j < 8; ++j) p[j] = (f16)tile[8 * q + j][c];
        const long long base =
            (((long long)(c0 + c) >> 7) * (long long)(R >> 5) + (r0 >> 5)) * 4096LL
            + q * 1024 + ((c0 + c) & 127) * 8;
        *reinterpret_cast<f16x8*>(&o[base]) = *reinterpret_cast<f16x8*>(p);
    }
}

// fp32 [R][1024] -> packed fp16 (K=1024), row-major pack (no transpose)
__global__ __launch_bounds__(256) void cvt_h_kernel(
    const float* __restrict__ in, f16* __restrict__ o, long long n)
{
    const long long i = ((long long)blockIdx.x * 256 + threadIdx.x) * 4;
    if (i >= n) return;
    const float4 v = *reinterpret_cast<const float4*>(in + i);
    f16 p[4] = {(f16)v.x, (f16)v.y, (f16)v.z, (f16)v.w};
    const long long r = i >> 10;
    const int k = (int)(i & 1023);
    *reinterpret_cast<f16x4*>(&o[paddr(r, k, 1024)]) = *reinterpret_cast<f16x4*>(p);
}

// zero-fill f16 buffer (n halves, multiple of 2048)
__global__ __launch_bounds__(256) void zero_h_kernel(f16* __restrict__ p, long long n)
{
    const long long i = ((long long)blockIdx.x * 256 + threadIdx.x) * 8;
    if (i >= n) return;
    f16x8 z = {};
    *reinterpret_cast<f16x8*>(p + i) = z;
}

// bias pad: out[0..63]=in, out[64..127]=0
__global__ __launch_bounds__(128) void pad_bias_kernel(
    const float* __restrict__ in, float* __restrict__ o)
{
    const int i = threadIdx.x;
    o[i] = (i < HH) ? in[i] : 0.0f;
}

// out[r] = scale * dot(W[r, 0:1024], v[0:1024]);  one wave per row
__global__ __launch_bounds__(256) void rowdot_kernel(
    const float* __restrict__ W, const float* __restrict__ v,
    float* __restrict__ out, float scale)
{
    const int row  = blockIdx.x * 4 + (threadIdx.x >> 6);
    const int lane = threadIdx.x & 63;
    const float* wr = W + (long long)row * 1024;
    float s = 0.0f;
    for (int k = lane; k < 1024; k += 64) s += wr[k] * v[k];
    #pragma unroll
    for (int off = 32; off; off >>= 1) s += __shfl_down(s, off);
    if (lane == 0) out[row] = s * scale;
}

// ---------------------------------------------------------------------------
// Single-pass LayerNorm over K=1024 on PACKED f16, in place, register-resident.
// Block = 32 rows (quarter of a 128-row group); 8 threads per row.
// ---------------------------------------------------------------------------
__global__ __launch_bounds__(256) void layernorm_pr_kernel(
    f16* __restrict__ x, const float* __restrict__ g, const float* __restrict__ b)
{
    const int grp = blockIdx.x >> 2;     // 128-row group
    const int qr  = blockIdx.x & 3;      // quarter: rows qr*32..+31
    f16* base = x + (long long)grp * 131072 + (qr * 32) * 8;
    const int t = threadIdx.x;
    const int r = t & 31;                // row within quarter
    const int s = t >> 5;                // 0..7 k-slice

    __shared__ float gs[1024], bs[1024];
    __shared__ float ssum[256], ssq[256];

    f16x8 vbuf[16];
    float sum = 0.0f, sq = 0.0f;
    #pragma unroll
    for (int i = 0; i < 16; ++i) {
        const int c = s * 16 + i;
        const int tile = c >> 2, q = c & 3;
        vbuf[i] = *reinterpret_cast<const f16x8*>(
            base + tile * 4096 + q * 1024 + r * 8);
        #pragma unroll
        for (int j = 0; j < 8; ++j) {
            const float f = (float)vbuf[i][j];
            sum += f; sq += f * f;
        }
    }
    for (int i = t; i < 1024; i += 256) { gs[i] = g[i]; bs[i] = b[i]; }
    ssum[t] = sum; ssq[t] = sq;
    __syncthreads();
    float rsum = 0.0f, rsq = 0.0f;
    #pragma unroll
    for (int ss = 0; ss < 8; ++ss) {
        rsum += ssum[ss * 32 + r];
        rsq  += ssq[ss * 32 + r];
    }
    const float mean = rsum * (1.0f / DD);
    const float var  = rsq * (1.0f / DD) - mean * mean;
    const float rstd = rsqrtf(fmaxf(var, 0.0f) + 1e-5f);

    #pragma unroll
    for (int i = 0; i < 16; ++i) {
        const int c = s * 16 + i;
        const int tile = c >> 2, q = c & 3;
        const int kbase = c * 8;
        f16 o[8];
        #pragma unroll
        for (int j = 0; j < 8; ++j)
            o[j] = (f16)(((float)vbuf[i][j] - mean) * rstd * gs[kbase + j]
                         + bs[kbase + j]);
        *reinterpret_cast<f16x8*>(base + tile * 4096 + q * 1024 + r * 8) =
            *reinterpret_cast<f16x8*>(o);
    }
}

// ---------------------------------------------------------------------------
// Row softmax over 512 cols, fp32 in -> packed fp16 (K=512)
// ---------------------------------------------------------------------------
__global__ __launch_bounds__(256) void softmax512_h_kernel(
    const float* __restrict__ x, f16* __restrict__ o)
{
    const long long row = blockIdx.x;
    const float2 v = reinterpret_cast<const float2*>(x + row * 512)[threadIdx.x];
    const int t = threadIdx.x;

    __shared__ float red[4];
    float mx = fmaxf(v.x, v.y);
    #pragma unroll
    for (int off = 32; off; off >>= 1) mx = fmaxf(mx, __shfl_down(mx, off));
    if ((t & 63) == 0) red[t >> 6] = mx;
    __syncthreads();
    mx = fmaxf(fmaxf(red[0], red[1]), fmaxf(red[2], red[3]));
    __syncthreads();

    const float e0 = expf(v.x - mx), e1 = expf(v.y - mx);
    float s = e0 + e1;
    #pragma unroll
    for (int off = 32; off; off >>= 1) s += __shfl_down(s, off);
    if ((t & 63) == 0) red[t >> 6] = s;
    __syncthreads();
    s = red[0] + red[1] + red[2] + red[3];
    const float inv = 1.0f / s;

    f16 p[2] = {(f16)(e0 * inv), (f16)(e1 * inv)};
    *reinterpret_cast<f16x2*>(&o[paddr(row, 2 * t, 512)]) =
        *reinterpret_cast<f16x2*>(p);
}

// fp32 row softmax over 512 in place (pool weights)
__global__ __launch_bounds__(256) void softmax512_kernel(float* __restrict__ x)
{
    const long long row = blockIdx.x;
    float2* xr = reinterpret_cast<float2*>(x + row * 512);
    const int t = threadIdx.x;
    float2 v = xr[t];

    __shared__ float red[4];
    float mx = fmaxf(v.x, v.y);
    #pragma unroll
    for (int off = 32; off; off >>= 1) mx = fmaxf(mx, __shfl_down(mx, off));
    if ((t & 63) == 0) red[t >> 6] = mx;
    __syncthreads();
    mx = fmaxf(fmaxf(red[0], red[1]), fmaxf(red[2], red[3]));
    __syncthreads();

    const float e0 = expf(v.x - mx), e1 = expf(v.y - mx);
    float s = e0 + e1;
    #pragma unroll
    for (int off = 32; off; off >>= 1) s += __shfl_down(s, off);
    if ((t & 63) == 0) red[t >> 6] = s;
    __syncthreads();
    s = red[0] + red[1] + red[2] + red[3];
    const float inv = 1.0f / s;
    xr[t] = make_float2(e0 * inv, e1 * inv);
}

// pool_scores[row] = h[row,:64] . Wp2 + bp2   (h row stride = 128)
__global__ __launch_bounds__(256) void pool_score_kernel(
    const float* __restrict__ h, const float* __restrict__ Wp2,
    const float* __restrict__ bp2, float* __restrict__ out)
{
    const int row  = blockIdx.x * 4 + (threadIdx.x >> 6);
    const int lane = threadIdx.x & 63;
    float v = h[(long long)row * 128 + lane] * Wp2[lane];
    #pragma unroll
    for (int off = 32; off; off >>= 1) v += __shfl_down(v, off);
    if (lane == 0) out[row] = v + bp2[0];
}

// pooled[b,d] = sum_n fused[b,n,d] * w[b,n]  -> packed f16 (r=b, K=1024)
__global__ __launch_bounds__(256) void pooled_kernel(
    const f16* __restrict__ fused, const float* __restrict__ w,
    f16* __restrict__ o)
{
    const int b = blockIdx.y;
    const int d = blockIdx.x * 256 + threadIdx.x;
    __shared__ float ws_[CC_];
    for (int i = threadIdx.x; i < CC_; i += 256) ws_[i] = w[(long long)b * CC_ + i];
    __syncthreads();
    const long long dpart = (long long)(d >> 5) * 4096
                          + ((d >> 3) & 3) * 1024 + (d & 7);
    float acc = 0.0f;
    for (int n = 0; n < CC_; ++n) {
        const long long r = (long long)b * CC_ + n;
        const long long addr = ((r >> 7) * 32) * 4096 + dpart + (r & 127) * 8;
        acc = fmaf((float)fused[addr], ws_[n], acc);
    }
    o[paddr(b, d, DD)] = (f16)acc;
}

// rul[b] = |h2[b,:] . Wf3 + bf3|
__global__ __launch_bounds__(256) void rul_kernel(
    const float* __restrict__ h2, const float* __restrict__ Wf3,
    const float* __restrict__ bf3, float* __restrict__ out)
{
    const int b = blockIdx.x;
    const int t = threadIdx.x;
    float acc = 0.0f;
    for (int k = t; k < DF_; k += 256)
        acc = fmaf(h2[(long long)b * DF_ + k], Wf3[k], acc);
    __shared__ float red[4];
    #pragma unroll
    for (int off = 32; off; off >>= 1) acc += __shfl_down(acc, off);
    if ((t & 63) == 0) red[t >> 6] = acc;
    __syncthreads();
    if (t == 0) out[b] = fabsf(red[0] + red[1] + red[2] + red[3] + bf3[0]);
}

// ---------------------------------------------------------------------------
// Launch
// ---------------------------------------------------------------------------
extern "C" void kernel_launch(void* const* d_in, const int* in_sizes, int n_in,
                              void* d_out, int out_size, void* d_ws, size_t ws_size,
                              hipStream_t stream)
{
    const float* x_enc   = (const float*)d_in[0];
    const float* W_emb   = (const float*)d_in[2];
    const float* b_emb   = (const float*)d_in[3];
    const float* g_s     = (const float*)d_in[4];
    const float* b_s     = (const float*)d_in[5];
    const float* basis   = (const float*)d_in[6];
    const float* Wq      = (const float*)d_in[7];
    const float* bq      = (const float*)d_in[8];
    const float* Wk      = (const float*)d_in[9];
    // bk (d_in[10]) and age_scale (d_in[13]) drop out of softmax (per-row consts)
    const float* Wv      = (const float*)d_in[11];
    const float* bv      = (const float*)d_in[12];
    const float* g_f     = (const float*)d_in[14];
    const float* b_f     = (const float*)d_in[15];
    const float* Wp1     = (const float*)d_in[16];
    const float* bp1     = (const float*)d_in[17];
    const float* Wp2     = (const float*)d_in[18];
    const float* bp2     = (const float*)d_in[19];
    const float* Wf1     = (const float*)d_in[20];
    const float* bf1     = (const float*)d_in[21];
    const float* Wf2     = (const float*)d_in[22];
    const float* bf2     = (const float*)d_in[23];
    const float* Wf3     = (const float*)d_in[24];
    const float* bf3     = (const float*)d_in[25];
    float* out = (float*)d_out;
    (void)in_sizes; (void)n_in; (void)out_size; (void)ws_size;

    // ---- workspace layout (MB offsets, liveness-reused; peak < 896 MB) ----
    const unsigned long long MBy = 1048576ULL;
    char* ws = (char*)d_ws;
    f16*  xT     = (f16*)(ws + 0 * MBy);       // packed [B] r=C,K=T (dead after sensor)
    f16*  WembT  = (f16*)(ws + 128 * MBy);     // packed r=D,K=T   2 MB
    f16*  Wqc    = (f16*)(ws + 130 * MBy);     // packed r=e(in),K=o  2 MB
    f16*  Wkc    = (f16*)(ws + 132 * MBy);     // packed r=i(in),K=o  2 MB
    f16*  Pt     = (f16*)(ws + 134 * MBy);     // packed r=i,K=e   2 MB (Wq Wk^T)^T
    f16*  W2t    = (f16*)(ws + 136 * MBy);     // packed r=m,K=e   1 MB (Wq bas^T)^T
    f16*  bas    = (f16*)(ws + 137 * MBy);     // packed r=C,K=D   1 MB
    f16*  Wp1p   = (f16*)(ws + 138 * MBy);     // packed r=128(pad),K=D
    float* bp1p  = (float*)(ws + 139 * MBy);   // padded bias [128]
    float* pbias = (float*)(ws + 139 * MBy + 4096);   // [1024]
    float* c2s   = (float*)(ws + 139 * MBy + 16384);  // [512]
    f16*  WvT    = (f16*)(ws + 140 * MBy);     // packed r=D,K=D   2 MB
    f16*  Wf1T   = (f16*)(ws + 142 * MBy);     // packed r=DF,K=D  4 MB
    f16*  Wf2T   = (f16*)(ws + 146 * MBy);     // packed r=DF,K=DF 8 MB
    f16*  sens   = (f16*)(ws + 256 * MBy);     // packed r=BC,K=D  (LN in place)
    f16*  QWp    = (f16*)(ws + 0 * MBy);       // packed r=BC,K=D (xT dead) 128 MB
    f16*  T1     = (f16*)(ws + 512 * MBy);     // packed [B] r=C,K=C  64 MB
    f16*  S2T    = (f16*)(ws + 640 * MBy);     // packed [B] r=C,K=C  64 MB
    float* S3    = (float*)(ws + 704 * MBy);   // [B][C][C] fp32  128 MB
    f16*  attn   = (f16*)(ws + 0 * MBy);       // packed r=BC,K=C (QWp dead)
    f16*  VT     = (f16*)(ws + 384 * MBy);     // packed [B] r=D,K=C  128 MB
    f16*  fusedp = (f16*)(ws + 512 * MBy);     // packed r=BC,K=D (T1/S2T dead)
    float* hpool = (float*)(ws + 704 * MBy);   // [BC][128] fp32 (S3 dead)
    float* pscr  = (float*)(ws + 840 * MBy);
    f16*  pooledp= (f16*)(ws + 842 * MBy);     // packed r=B(128),K=D  256 KB
    f16*  h1p    = (f16*)(ws + 844 * MBy);     // packed r=B,K=DF  512 KB
    float* h2    = (float*)(ws + 848 * MBy);   // [B][DF] fp32  1 MB

    const long long CD  = (long long)CC_ * DD;   // 524288
    const long long CCs = (long long)CC_ * CC_;  // 262144
    const long long DC  = (long long)DD * CC_;
    const dim3 blk(256);

    // ---- upfront prep ----
    transpose_h_kernel<<<dim3(CC_ / 32, TT / 32, BB), blk, 0, stream>>>(
        x_enc, xT, TT, CC_, (long long)TT * CC_, (long long)CC_ * TT);
    transpose_h_kernel<<<dim3(DD / 32, TT / 32, 1), blk, 0, stream>>>(
        W_emb, WembT, TT, DD, 0, 0);
    transpose_h_kernel<<<dim3(DD / 32, DD / 32, 1), blk, 0, stream>>>(
        Wv, WvT, DD, DD, 0, 0);
    transpose_h_kernel<<<dim3(DF_ / 32, DD / 32, 1), blk, 0, stream>>>(
        Wf1, Wf1T, DD, DF_, 0, 0);
    transpose_h_kernel<<<dim3(DF_ / 32, DF_ / 32, 1), blk, 0, stream>>>(
        Wf2, Wf2T, DF_, DF_, 0, 0);
    cvt_h_kernel<<<(DD * DD) / 1024, blk, 0, stream>>>(Wq, Wqc, (long long)DD * DD);
    cvt_h_kernel<<<(DD * DD) / 1024, blk, 0, stream>>>(Wk, Wkc, (long long)DD * DD);
    cvt_h_kernel<<<(CC_ * DD) / 1024, blk, 0, stream>>>(
        basis, bas, (long long)CC_ * DD);
    zero_h_kernel<<<64, blk, 0, stream>>>(Wp1p, 131072);
    transpose_h_kernel<<<dim3(HH / 32, DD / 32, 1), blk, 0, stream>>>(
        Wp1, Wp1p, DD, HH, 0, 0);
    pad_bias_kernel<<<1, 128, 0, stream>>>(bp1, bp1p);
    // pbias[i] = Wk[i,:] . bq ;  c2s[m] = s * (basis[m,:] . bq)
    rowdot_kernel<<<DD / 4, blk, 0, stream>>>(Wk, bq, pbias, 1.0f);
    rowdot_kernel<<<CC_ / 4, blk, 0, stream>>>(basis, bq, c2s, INV_SQRT_D);
    // P^T: P[e,i] = sum_o Wq[e,o] Wk[i,o]; OUT=2 -> packed(r=i, k=e)
    mfma_gemm<2><<<dim3(DD / 128, DD / 128, 1), blk, 0, stream>>>(
        Wqc, Wkc, nullptr, nullptr, Pt, DD, DD, DD, 0, 0, 0, 1.0f);
    // W2^T: W2[e,m] = sum_o Wq[e,o] bas[m,o]; OUT=2 -> packed(r=m, k=e)
    mfma_gemm<2><<<dim3(CC_ / 128, DD / 128, 1), blk, 0, stream>>>(
        Wqc, bas, nullptr, nullptr, W2t, DD, CC_, DD, 0, 0, 0, 1.0f);

    // ---- main pipeline ----
    // sensor = xT @ WembT^T + b_emb -> packed f16
    mfma_gemm<1><<<dim3(DD / 128, CC_ / 128, BB), blk, 0, stream>>>(
        xT, WembT, b_emb, nullptr, sens,
        CC_, DD, TT, (long long)CC_ * TT, 0, CD, 1.0f);
    layernorm_pr_kernel<<<(BB * CC_) / 32, blk, 0, stream>>>(sens, g_s, b_s);
    // QW = sens @ P + pbias -> packed (r=BC, K=D)   [= Q Wk^T exactly]
    mfma_gemm<1><<<dim3(DD / 128, (BB * CC_) / 128, 1), blk, 0, stream>>>(
        sens, Pt, pbias, nullptr, QWp,
        BB * CC_, DD, DD, 0, 0, 0, 1.0f);
    // S2T = (s*(sens @ W2) + s*c2)^T packed (rows m, K=C) per batch [= age_bias^T]
    mfma_gemm<2><<<dim3(CC_ / 128, CC_ / 128, BB), blk, 0, stream>>>(
        sens, W2t, c2s, nullptr, S2T,
        CC_, CC_, DD, CD, 0, CCs, INV_SQRT_D);
    // T1 = (s * QW @ sens^T)^T packed (rows k, K=C) per batch
    mfma_gemm<2><<<dim3(CC_ / 128, CC_ / 128, BB), blk, 0, stream>>>(
        QWp, sens, nullptr, nullptr, T1,
        CC_, CC_, DD, CD, CD, CCs, INV_SQRT_D);
    // S3[n,k] = sum_j S2T[n,j]*T1[k,j]   (fp32 out)
    mfma_gemm<0><<<dim3(CC_ / 128, CC_ / 128, BB), blk, 0, stream>>>(
        S2T, T1, nullptr, nullptr, S3,
        CC_, CC_, CC_, CCs, CCs, CCs, 1.0f);
    // attn = softmax(S3) -> packed fp16 (rows flat BC, K=C)
    softmax512_h_kernel<<<BB * CC_, blk, 0, stream>>>(S3, attn);
    // VT = (sensor @ Wv + bv)^T packed (rows D, K=C) per batch
    mfma_gemm<2><<<dim3(DD / 128, CC_ / 128, BB), blk, 0, stream>>>(
        sens, WvT, bv, nullptr, VT,
        CC_, DD, DD, CD, 0, DC, 1.0f);
    // fused = attn @ VT^T / 32 -> packed f16 (rows flat BC, K=D)
    mfma_gemm<1><<<dim3(DD / 128, CC_ / 128, BB), blk, 0, stream>>>(
        attn, VT, nullptr, nullptr, fusedp,
        CC_, DD, CC_, CCs, DC, CD, INV_SQRT_D);
    layernorm_pr_kernel<<<(BB * CC_) / 32, blk, 0, stream>>>(fusedp, g_f, b_f);
    // hpool = gelu(fused @ Wp1 + bp1)  (MFMA, padded N=128)
    mfma_gemm<0, 2><<<dim3(1, (BB * CC_) / 128, 1), blk, 0, stream>>>(
        fusedp, Wp1p, bp1p, nullptr, hpool,
        BB * CC_, 128, DD, 0, 0, 0, 1.0f);
    // pool scores + softmax over C
    pool_score_kernel<<<(BB * CC_) / 4, blk, 0, stream>>>(hpool, Wp2, bp2, pscr);
    softmax512_kernel<<<BB, blk, 0, stream>>>(pscr);
    // pooled (reads packed fused) -> packed f16
    pooled_kernel<<<dim3(DD / 256, BB), blk, 0, stream>>>(fusedp, pscr, pooledp);
    // fc head on MFMA:
    // h1 = leaky_relu(pooled @ Wf1 + bf1) -> packed (r=B, K=DF)
    mfma_gemm<1, 1><<<dim3(DF_ / 128, BB / 128, 1), blk, 0, stream>>>(
        pooledp, Wf1T, bf1, nullptr, h1p,
        BB, DF_, DD, 0, 0, 0, 1.0f);
    // h2 = h1 @ Wf2 + bf2  (fp32 out)
    mfma_gemm<0><<<dim3(DF_ / 128, BB / 128, 1), blk, 0, stream>>>(
        h1p, Wf2T, bf2, nullptr, h2,
        BB, DF_, DF_, 0, 0, 0, 1.0f);
    rul_kernel<<<BB, blk, 0, stream>>>(h2, Wf3, bf3, out);
}

// Round 21
// 1306.776 us; speedup vs baseline: 1.2036x; 1.0124x over previous
//
#include <hip/hip_runtime.h>
#include <hip/hip_bf16.h>
#include <math.h>

// ---------------------------------------------------------------------------
// Problem constants
// ---------------------------------------------------------------------------
#define BB   128     // batch
#define TT   1024    // time
#define CC_  512     // channels / variates (N)
#define DD   1024    // model dim
#define DF_  2048    // fc hidden
#define HH   64      // pool hidden
#define INV_SQRT_D 0.03125f   // 1/sqrt(1024)

typedef _Float16 f16;
typedef __attribute__((ext_vector_type(8))) _Float16 f16x8;
typedef __attribute__((ext_vector_type(4))) _Float16 f16x4;
typedef __attribute__((ext_vector_type(2))) _Float16 f16x2;
typedef __attribute__((ext_vector_type(4))) float f32x4;

__device__ __forceinline__ void gload_lds16(const void* g, void* l) {
    // async global->LDS, 16B per lane; LDS dest = wave-uniform base + lane*16
    __builtin_amdgcn_global_load_lds(
        (const __attribute__((address_space(1))) void*)g,
        (__attribute__((address_space(3))) void*)l, 16, 0, 0);
}

// Tile-packed operand layout (half-element index).  For a GEMM operand with
// row dim r (tiles of 128) and contraction dim k (tiles of 32, sub-chunks
// of 8): element (r,k) lives at
//   ((r>>7)*(K>>5) + (k>>5))*4096 + ((k>>3)&3)*1024 + (r&127)*8 + (k&7)
__device__ __forceinline__ long long paddr(long long r, int k, int K) {
    return ((r >> 7) * (long long)(K >> 5) + (k >> 5)) * 4096LL
         + (long long)(((k >> 3) & 3) * 1024 + ((int)(r & 127)) * 8 + (k & 7));
}

// ---------------------------------------------------------------------------
// fp16 MFMA GEMM (fp32 accumulate), 128x128 tile, BK=64, 4 waves,
// single-buffered 2-barrier loop, PACKED operands.
//   C[m,n] = act(alpha*sum_k A[m,k]*B[n,k] + add_c + bias[n])
//   OUT: 0 = fp32 C[M][N] row-major;  1 = packed f16 (r=m, k=n, K=N);
//        2 = packed f16 transposed (r=n, k=m, K=M)
//   ACT: 0 = none, 1 = leaky_relu(0.01), 2 = exact gelu
// M,N multiples of 128; K multiple of 64.
// ---------------------------------------------------------------------------
template <int OUT, int ACT = 0>
__global__ __launch_bounds__(256, 4) void mfma_gemm(
    const f16* __restrict__ A, const f16* __restrict__ B,
    const float* __restrict__ bias, const float* __restrict__ add_c,
    void* __restrict__ C0,
    int M, int N, int K,
    long long sA, long long sB, long long sC, float alpha)
{
    // ---- XCD swizzle on flattened (x,y); identity when nwg % 8 != 0 ----
    const int gx = gridDim.x;
    const int nwg = gx * gridDim.y;
    int lin = blockIdx.y * gx + blockIdx.x;
    if ((nwg & 7) == 0) {
        const int cpx = nwg >> 3;
        lin = (lin & 7) * cpx + (lin >> 3);
    }
    const int bx = lin % gx, by = lin / gx;

    const int bz   = blockIdx.z;
    const int t    = threadIdx.x;
    const int wave = t >> 6, lane = t & 63;
    const int m0 = by * 128, n0 = bx * 128;
    const int wm = (wave >> 1) * 64, wn = (wave & 1) * 64;

    __shared__ __align__(16) f16 As[2][4096];   // 8 KB per sub-tile
    __shared__ __align__(16) f16 Bs[2][4096];

    f32x4 acc[4][4] = {};

    const int wbyte = wave * 1024;               // wave-uniform LDS base
    const long long tA = (long long)bz * sA + (long long)(m0 >> 7) * (K >> 5) * 4096;
    const long long tB = (long long)bz * sB + (long long)(n0 >> 7) * (K >> 5) * 4096;
    const f16* pA = A + tA + t * 8;
    const f16* pB = B + tB + t * 8;

    const int q   = lane >> 4;   // k-chunk for fragment reads
    const int r16 = lane & 15;

    for (int k0 = 0; k0 < K; k0 += 64) {
        const long long ko = (long long)(k0 >> 5) * 4096;
        __syncthreads();                       // previous compute done
        gload_lds16(pA + ko,        (char*)(&As[0][0]) + wbyte);
        gload_lds16(pA + ko + 2048, (char*)(&As[0][0]) + wbyte + 4096);
        gload_lds16(pA + ko + 4096, (char*)(&As[1][0]) + wbyte);
        gload_lds16(pA + ko + 6144, (char*)(&As[1][0]) + wbyte + 4096);
        gload_lds16(pB + ko,        (char*)(&Bs[0][0]) + wbyte);
        gload_lds16(pB + ko + 2048, (char*)(&Bs[0][0]) + wbyte + 4096);
        gload_lds16(pB + ko + 4096, (char*)(&Bs[1][0]) + wbyte);
        gload_lds16(pB + ko + 6144, (char*)(&Bs[1][0]) + wbyte + 4096);
        __syncthreads();                       // drains vmcnt: tiles ready

        #pragma unroll
        for (int s = 0; s < 2; ++s) {
            const f16x8* AV = (const f16x8*)(&As[s][0]);
            const f16x8* BV = (const f16x8*)(&Bs[s][0]);
            f16x8 bfr[4];
            #pragma unroll
            for (int j = 0; j < 4; ++j)
                bfr[j] = BV[q * 128 + wn + j * 16 + r16];
            __builtin_amdgcn_s_setprio(1);
            #pragma unroll
            for (int i = 0; i < 4; ++i) {
                const f16x8 a = AV[q * 128 + wm + i * 16 + r16];
                #pragma unroll
                for (int j = 0; j < 4; ++j)
                    acc[i][j] = __builtin_amdgcn_mfma_f32_16x16x32_f16(
                        a, bfr[j], acc[i][j], 0, 0, 0);
            }
            __builtin_amdgcn_s_setprio(0);
        }
    }

    // epilogue: C/D layout col = lane&15, row = (lane>>4)*4 + r
    const float cadd = add_c ? add_c[0] : 0.0f;
    const int col = lane & 15;
    const int rb  = (lane >> 4) * 4;
    #pragma unroll
    for (int j = 0; j < 4; ++j) {
        const int n = n0 + wn + j * 16 + col;
        const float bv = bias ? bias[n] : 0.0f;
        #pragma unroll
        for (int i = 0; i < 4; ++i) {
            const int m = m0 + wm + i * 16 + rb;
            f32x4 v = acc[i][j];
            #pragma unroll
            for (int r = 0; r < 4; ++r) {
                v[r] = v[r] * alpha + cadd + bv;
                if constexpr (ACT == 1)
                    v[r] = (v[r] > 0.0f) ? v[r] : 0.01f * v[r];
                else if constexpr (ACT == 2)
                    v[r] = 0.5f * v[r] * (1.0f + erff(v[r] * 0.70710678118654752f));
            }
            if constexpr (OUT == 0) {
                float* C = (float*)C0 + (long long)bz * sC;
                #pragma unroll
                for (int r = 0; r < 4; ++r) C[(long long)(m + r) * N + n] = v[r];
            } else if constexpr (OUT == 1) {
                // packed: (r=m+r, k=n), K=N
                f16* C = (f16*)C0 + (long long)bz * sC;
                #pragma unroll
                for (int r = 0; r < 4; ++r)
                    C[paddr(m + r, n, N)] = (f16)v[r];
            } else {
                // packed transposed: (r=n, k=m..m+3), K=M;  m%8 in {0,4}
                f16* C = (f16*)C0 + (long long)bz * sC;
                f16 p[4];
                #pragma unroll
                for (int r = 0; r < 4; ++r) p[r] = (f16)v[r];
                *reinterpret_cast<f16x4*>(&C[paddr(n, m, M)]) =
                    *reinterpret_cast<f16x4*>(p);
            }
        }
    }
}

// ---------------------------------------------------------------------------
// Fused pool-score GEMM: pscr[m] = sum_{n<64} gelu((fused@Wp1p)[m,n]+bp1[n])
//                                  * Wp2[n] + bp2.
// Same loop as mfma_gemm with N=128 (Wp1p zero-padded rows 64..127), grid =
// (BC/128) blocks; wn==0 waves hold cols 0..63 and reduce via shfl_xor.
// ---------------------------------------------------------------------------
__global__ __launch_bounds__(256, 4) void pool_fused_kernel(
    const f16* __restrict__ A, const f16* __restrict__ B,
    const float* __restrict__ bp1, const float* __restrict__ Wp2,
    const float* __restrict__ bp2, float* __restrict__ pscr, int K)
{
    const int t    = threadIdx.x;
    const int wave = t >> 6, lane = t & 63;
    const int m0 = blockIdx.x * 128;
    const int wm = (wave >> 1) * 64, wn = (wave & 1) * 64;

    __shared__ __align__(16) f16 As[2][4096];
    __shared__ __align__(16) f16 Bs[2][4096];

    f32x4 acc[4][4] = {};

    const int wbyte = wave * 1024;
    const long long tA = (long long)(m0 >> 7) * (K >> 5) * 4096;
    const f16* pA = A + tA + t * 8;
    const f16* pB = B + t * 8;

    const int q   = lane >> 4;
    const int r16 = lane & 15;

    for (int k0 = 0; k0 < K; k0 += 64) {
        const long long ko = (long long)(k0 >> 5) * 4096;
        __syncthreads();
        gload_lds16(pA + ko,        (char*)(&As[0][0]) + wbyte);
        gload_lds16(pA + ko + 2048, (char*)(&As[0][0]) + wbyte + 4096);
        gload_lds16(pA + ko + 4096, (char*)(&As[1][0]) + wbyte);
        gload_lds16(pA + ko + 6144, (char*)(&As[1][0]) + wbyte + 4096);
        gload_lds16(pB + ko,        (char*)(&Bs[0][0]) + wbyte);
        gload_lds16(pB + ko + 2048, (char*)(&Bs[0][0]) + wbyte + 4096);
        gload_lds16(pB + ko + 4096, (char*)(&Bs[1][0]) + wbyte);
        gload_lds16(pB + ko + 6144, (char*)(&Bs[1][0]) + wbyte + 4096);
        __syncthreads();

        #pragma unroll
        for (int s = 0; s < 2; ++s) {
            const f16x8* AV = (const f16x8*)(&As[s][0]);
            const f16x8* BV = (const f16x8*)(&Bs[s][0]);
            f16x8 bfr[4];
            #pragma unroll
            for (int j = 0; j < 4; ++j)
                bfr[j] = BV[q * 128 + wn + j * 16 + r16];
            __builtin_amdgcn_s_setprio(1);
            #pragma unroll
            for (int i = 0; i < 4; ++i) {
                const f16x8 a = AV[q * 128 + wm + i * 16 + r16];
                #pragma unroll
                for (int j = 0; j < 4; ++j)
                    acc[i][j] = __builtin_amdgcn_mfma_f32_16x16x32_f16(
                        a, bfr[j], acc[i][j], 0, 0, 0);
            }
            __builtin_amdgcn_s_setprio(0);
        }
    }

    // epilogue: only wn==0 waves hold cols 0..63 (Wp2 support)
    if (wn == 0) {
        const int col = lane & 15;
        const int rb  = (lane >> 4) * 4;
        #pragma unroll
        for (int i = 0; i < 4; ++i) {
            f32x4 rsum = {};
            #pragma unroll
            for (int j = 0; j < 4; ++j) {
                const int n = j * 16 + col;          // < 64
                const float bv = bp1[n];
                const float w2 = Wp2[n];
                #pragma unroll
                for (int r = 0; r < 4; ++r) {
                    float v = acc[i][j][r] + bv;
                    v = 0.5f * v * (1.0f + erff(v * 0.70710678118654752f));
                    rsum[r] = fmaf(v, w2, rsum[r]);
                }
            }
            #pragma unroll
            for (int off = 1; off < 16; off <<= 1) {
                #pragma unroll
                for (int r = 0; r < 4; ++r)
                    rsum[r] += __shfl_xor(rsum[r], off);
            }
            if (col == 0) {
                #pragma unroll
                for (int r = 0; r < 4; ++r)
                    pscr[m0 + wm + i * 16 + rb + r] = rsum[r] + bp2[0];
            }
        }
    }
}

// ---------------------------------------------------------------------------
// fp32 [R][Cc] -> packed fp16 (rows = Cc-dim, k = original row dim, len R).
// value for output (row c0+c, k r0+8q+j) = tile[8q+j][c].
// ---------------------------------------------------------------------------
__global__ __launch_bounds__(256) void transpose_h_kernel(
    const float* __restrict__ in, f16* __restrict__ o,
    int R, int Cc, long long sIn, long long sOut)
{
    const int b = blockIdx.z;
    in += (long long)b * sIn; o += (long long)b * sOut;
    __shared__ float tile[32][33];
    const int c0 = blockIdx.x * 32, r0 = blockIdx.y * 32;
    const int tx = threadIdx.x & 31, ty = threadIdx.x >> 5;   // 32 x 8
    #pragma unroll
    for (int i = 0; i < 32; i += 8)
        tile[ty + i][tx] = in[(long long)(r0 + ty + i) * Cc + (c0 + tx)];
    __syncthreads();
    if (threadIdx.x < 128) {
        const int c = threadIdx.x & 31, q = threadIdx.x >> 5;
        f16 p[8];
        #pragma unroll
        for (int j = 0; j < 8; ++j) p[j] = (f16)tile[8 * q + j][c];
        const long long base =
            (((long long)(c0 + c) >> 7) * (long long)(R >> 5) + (r0 >> 5)) * 4096LL
            + q * 1024 + ((c0 + c) & 127) * 8;
        *reinterpret_cast<f16x8*>(&o[base]) = *reinterpret_cast<f16x8*>(p);
    }
}

// fp32 [R][1024] -> packed fp16 (K=1024), row-major pack (no transpose)
__global__ __launch_bounds__(256) void cvt_h_kernel(
    const float* __restrict__ in, f16* __restrict__ o, long long n)
{
    const long long i = ((long long)blockIdx.x * 256 + threadIdx.x) * 4;
    if (i >= n) return;
    const float4 v = *reinterpret_cast<const float4*>(in + i);
    f16 p[4] = {(f16)v.x, (f16)v.y, (f16)v.z, (f16)v.w};
    const long long r = i >> 10;
    const int k = (int)(i & 1023);
    *reinterpret_cast<f16x4*>(&o[paddr(r, k, 1024)]) = *reinterpret_cast<f16x4*>(p);
}

// zero-fill f16 buffer (n halves, multiple of 2048)
__global__ __launch_bounds__(256) void zero_h_kernel(f16* __restrict__ p, long long n)
{
    const long long i = ((long long)blockIdx.x * 256 + threadIdx.x) * 8;
    if (i >= n) return;
    f16x8 z = {};
    *reinterpret_cast<f16x8*>(p + i) = z;
}

// out[r] = scale * dot(W[r, 0:1024], v[0:1024]);  one wave per row
__global__ __launch_bounds__(256) void rowdot_kernel(
    const float* __restrict__ W, const float* __restrict__ v,
    float* __restrict__ out, float scale)
{
    const int row  = blockIdx.x * 4 + (threadIdx.x >> 6);
    const int lane = threadIdx.x & 63;
    const float* wr = W + (long long)row * 1024;
    float s = 0.0f;
    for (int k = lane; k < 1024; k += 64) s += wr[k] * v[k];
    #pragma unroll
    for (int off = 32; off; off >>= 1) s += __shfl_down(s, off);
    if (lane == 0) out[row] = s * scale;
}

// ---------------------------------------------------------------------------
// Single-pass LayerNorm over K=1024 on PACKED f16, in place, register-resident.
// Block = 32 rows (quarter of a 128-row group); 8 threads per row.
// ---------------------------------------------------------------------------
__global__ __launch_bounds__(256) void layernorm_pr_kernel(
    f16* __restrict__ x, const float* __restrict__ g, const float* __restrict__ b)
{
    const int grp = blockIdx.x >> 2;     // 128-row group
    const int qr  = blockIdx.x & 3;      // quarter: rows qr*32..+31
    f16* base = x + (long long)grp * 131072 + (qr * 32) * 8;
    const int t = threadIdx.x;
    const int r = t & 31;                // row within quarter
    const int s = t >> 5;                // 0..7 k-slice

    __shared__ float gs[1024], bs[1024];
    __shared__ float ssum[256], ssq[256];

    f16x8 vbuf[16];
    float sum = 0.0f, sq = 0.0f;
    #pragma unroll
    for (int i = 0; i < 16; ++i) {
        const int c = s * 16 + i;
        const int tile = c >> 2, q = c & 3;
        vbuf[i] = *reinterpret_cast<const f16x8*>(
            base + tile * 4096 + q * 1024 + r * 8);
        #pragma unroll
        for (int j = 0; j < 8; ++j) {
            const float f = (float)vbuf[i][j];
            sum += f; sq += f * f;
        }
    }
    for (int i = t; i < 1024; i += 256) { gs[i] = g[i]; bs[i] = b[i]; }
    ssum[t] = sum; ssq[t] = sq;
    __syncthreads();
    float rsum = 0.0f, rsq = 0.0f;
    #pragma unroll
    for (int ss = 0; ss < 8; ++ss) {
        rsum += ssum[ss * 32 + r];
        rsq  += ssq[ss * 32 + r];
    }
    const float mean = rsum * (1.0f / DD);
    const float var  = rsq * (1.0f / DD) - mean * mean;
    const float rstd = rsqrtf(fmaxf(var, 0.0f) + 1e-5f);

    #pragma unroll
    for (int i = 0; i < 16; ++i) {
        const int c = s * 16 + i;
        const int tile = c >> 2, q = c & 3;
        const int kbase = c * 8;
        f16 o[8];
        #pragma unroll
        for (int j = 0; j < 8; ++j)
            o[j] = (f16)(((float)vbuf[i][j] - mean) * rstd * gs[kbase + j]
                         + bs[kbase + j]);
        *reinterpret_cast<f16x8*>(base + tile * 4096 + q * 1024 + r * 8) =
            *reinterpret_cast<f16x8*>(o);
    }
}

// ---------------------------------------------------------------------------
// Row softmax over 512 cols, fp32 in -> packed fp16 (K=512)
// ---------------------------------------------------------------------------
__global__ __launch_bounds__(256) void softmax512_h_kernel(
    const float* __restrict__ x, f16* __restrict__ o)
{
    const long long row = blockIdx.x;
    const float2 v = reinterpret_cast<const float2*>(x + row * 512)[threadIdx.x];
    const int t = threadIdx.x;

    __shared__ float red[4];
    float mx = fmaxf(v.x, v.y);
    #pragma unroll
    for (int off = 32; off; off >>= 1) mx = fmaxf(mx, __shfl_down(mx, off));
    if ((t & 63) == 0) red[t >> 6] = mx;
    __syncthreads();
    mx = fmaxf(fmaxf(red[0], red[1]), fmaxf(red[2], red[3]));
    __syncthreads();

    const float e0 = expf(v.x - mx), e1 = expf(v.y - mx);
    float s = e0 + e1;
    #pragma unroll
    for (int off = 32; off; off >>= 1) s += __shfl_down(s, off);
    if ((t & 63) == 0) red[t >> 6] = s;
    __syncthreads();
    s = red[0] + red[1] + red[2] + red[3];
    const float inv = 1.0f / s;

    f16 p[2] = {(f16)(e0 * inv), (f16)(e1 * inv)};
    *reinterpret_cast<f16x2*>(&o[paddr(row, 2 * t, 512)]) =
        *reinterpret_cast<f16x2*>(p);
}

// fp32 row softmax over 512 in place (pool weights)
__global__ __launch_bounds__(256) void softmax512_kernel(float* __restrict__ x)
{
    const long long row = blockIdx.x;
    float2* xr = reinterpret_cast<float2*>(x + row * 512);
    const int t = threadIdx.x;
    float2 v = xr[t];

    __shared__ float red[4];
    float mx = fmaxf(v.x, v.y);
    #pragma unroll
    for (int off = 32; off; off >>= 1) mx = fmaxf(mx, __shfl_down(mx, off));
    if ((t & 63) == 0) red[t >> 6] = mx;
    __syncthreads();
    mx = fmaxf(fmaxf(red[0], red[1]), fmaxf(red[2], red[3]));
    __syncthreads();

    const float e0 = expf(v.x - mx), e1 = expf(v.y - mx);
    float s = e0 + e1;
    #pragma unroll
    for (int off = 32; off; off >>= 1) s += __shfl_down(s, off);
    if ((t & 63) == 0) red[t >> 6] = s;
    __syncthreads();
    s = red[0] + red[1] + red[2] + red[3];
    const float inv = 1.0f / s;
    xr[t] = make_float2(e0 * inv, e1 * inv);
}

// pooled[b,d] = sum_n fused[b,n,d] * w[b,n]  -> packed f16 (r=b, K=1024)
__global__ __launch_bounds__(256) void pooled_kernel(
    const f16* __restrict__ fused, const float* __restrict__ w,
    f16* __restrict__ o)
{
    const int b = blockIdx.y;
    const int d = blockIdx.x * 256 + threadIdx.x;
    __shared__ float ws_[CC_];
    for (int i = threadIdx.x; i < CC_; i += 256) ws_[i] = w[(long long)b * CC_ + i];
    __syncthreads();
    const long long dpart = (long long)(d >> 5) * 4096
                          + ((d >> 3) & 3) * 1024 + (d & 7);
    float acc = 0.0f;
    for (int n = 0; n < CC_; ++n) {
        const long long r = (long long)b * CC_ + n;
        const long long addr = ((r >> 7) * 32) * 4096 + dpart + (r & 127) * 8;
        acc = fmaf((float)fused[addr], ws_[n], acc);
    }
    o[paddr(b, d, DD)] = (f16)acc;
}

// rul[b] = |h2[b,:] . Wf3 + bf3|
__global__ __launch_bounds__(256) void rul_kernel(
    const float* __restrict__ h2, const float* __restrict__ Wf3,
    const float* __restrict__ bf3, float* __restrict__ out)
{
    const int b = blockIdx.x;
    const int t = threadIdx.x;
    float acc = 0.0f;
    for (int k = t; k < DF_; k += 256)
        acc = fmaf(h2[(long long)b * DF_ + k], Wf3[k], acc);
    __shared__ float red[4];
    #pragma unroll
    for (int off = 32; off; off >>= 1) acc += __shfl_down(acc, off);
    if ((t & 63) == 0) red[t >> 6] = acc;
    __syncthreads();
    if (t == 0) out[b] = fabsf(red[0] + red[1] + red[2] + red[3] + bf3[0]);
}

// ---------------------------------------------------------------------------
// Launch
// ---------------------------------------------------------------------------
extern "C" void kernel_launch(void* const* d_in, const int* in_sizes, int n_in,
                              void* d_out, int out_size, void* d_ws, size_t ws_size,
                              hipStream_t stream)
{
    const float* x_enc   = (const float*)d_in[0];
    const float* W_emb   = (const float*)d_in[2];
    const float* b_emb   = (const float*)d_in[3];
    const float* g_s     = (const float*)d_in[4];
    const float* b_s     = (const float*)d_in[5];
    const float* basis   = (const float*)d_in[6];
    const float* Wq      = (const float*)d_in[7];
    const float* bq      = (const float*)d_in[8];
    const float* Wk      = (const float*)d_in[9];
    // bk (d_in[10]) and age_scale (d_in[13]) drop out of softmax (per-row consts)
    const float* Wv      = (const float*)d_in[11];
    const float* bv      = (const float*)d_in[12];
    const float* g_f     = (const float*)d_in[14];
    const float* b_f     = (const float*)d_in[15];
    const float* Wp1     = (const float*)d_in[16];
    const float* bp1     = (const float*)d_in[17];
    const float* Wp2     = (const float*)d_in[18];
    const float* bp2     = (const float*)d_in[19];
    const float* Wf1     = (const float*)d_in[20];
    const float* bf1     = (const float*)d_in[21];
    const float* Wf2     = (const float*)d_in[22];
    const float* bf2     = (const float*)d_in[23];
    const float* Wf3     = (const float*)d_in[24];
    const float* bf3     = (const float*)d_in[25];
    float* out = (float*)d_out;
    (void)in_sizes; (void)n_in; (void)out_size; (void)ws_size;

    // ---- workspace layout (MB offsets, liveness-reused; peak < 896 MB) ----
    const unsigned long long MBy = 1048576ULL;
    char* ws = (char*)d_ws;
    f16*  xT     = (f16*)(ws + 0 * MBy);       // packed [B] r=C,K=T (dead after sensor)
    f16*  WembT  = (f16*)(ws + 128 * MBy);     // packed r=D,K=T   2 MB
    f16*  Wqc    = (f16*)(ws + 130 * MBy);     // packed r=e(in),K=o  2 MB
    f16*  Wkc    = (f16*)(ws + 132 * MBy);     // packed r=i(in),K=o  2 MB
    f16*  Pt     = (f16*)(ws + 134 * MBy);     // packed r=i,K=e   2 MB (Wq Wk^T)^T
    f16*  W2t    = (f16*)(ws + 136 * MBy);     // packed r=m,K=e   1 MB (Wq bas^T)^T
    f16*  bas    = (f16*)(ws + 137 * MBy);     // packed r=C,K=D   1 MB
    f16*  Wp1p   = (f16*)(ws + 138 * MBy);     // packed r=128(pad),K=D
    float* pbias = (float*)(ws + 139 * MBy + 4096);   // [1024]
    float* c2s   = (float*)(ws + 139 * MBy + 16384);  // [512]
    f16*  WvT    = (f16*)(ws + 140 * MBy);     // packed r=D,K=D   2 MB
    f16*  Wf1T   = (f16*)(ws + 142 * MBy);     // packed r=DF,K=D  4 MB
    f16*  Wf2T   = (f16*)(ws + 146 * MBy);     // packed r=DF,K=DF 8 MB
    f16*  sens   = (f16*)(ws + 256 * MBy);     // packed r=BC,K=D  (LN in place)
    f16*  QWp    = (f16*)(ws + 0 * MBy);       // packed r=BC,K=D (xT dead) 128 MB
    f16*  T1     = (f16*)(ws + 512 * MBy);     // packed [B] r=C,K=C  64 MB
    f16*  S2T    = (f16*)(ws + 640 * MBy);     // packed [B] r=C,K=C  64 MB
    float* S3    = (float*)(ws + 704 * MBy);   // [B][C][C] fp32  128 MB
    f16*  attn   = (f16*)(ws + 0 * MBy);       // packed r=BC,K=C (QWp dead)
    f16*  VT     = (f16*)(ws + 384 * MBy);     // packed [B] r=D,K=C  128 MB
    f16*  fusedp = (f16*)(ws + 512 * MBy);     // packed r=BC,K=D (T1/S2T dead)
    float* pscr  = (float*)(ws + 840 * MBy);
    f16*  pooledp= (f16*)(ws + 842 * MBy);     // packed r=B(128),K=D  256 KB
    f16*  h1p    = (f16*)(ws + 844 * MBy);     // packed r=B,K=DF  512 KB
    float* h2    = (float*)(ws + 848 * MBy);   // [B][DF] fp32  1 MB

    const long long CD  = (long long)CC_ * DD;   // 524288
    const long long CCs = (long long)CC_ * CC_;  // 262144
    const long long DC  = (long long)DD * CC_;
    const dim3 blk(256);

    // ---- upfront prep ----
    transpose_h_kernel<<<dim3(CC_ / 32, TT / 32, BB), blk, 0, stream>>>(
        x_enc, xT, TT, CC_, (long long)TT * CC_, (long long)CC_ * TT);
    transpose_h_kernel<<<dim3(DD / 32, TT / 32, 1), blk, 0, stream>>>(
        W_emb, WembT, TT, DD, 0, 0);
    transpose_h_kernel<<<dim3(DD / 32, DD / 32, 1), blk, 0, stream>>>(
        Wv, WvT, DD, DD, 0, 0);
    transpose_h_kernel<<<dim3(DF_ / 32, DD / 32, 1), blk, 0, stream>>>(
        Wf1, Wf1T, DD, DF_, 0, 0);
    transpose_h_kernel<<<dim3(DF_ / 32, DF_ / 32, 1), blk, 0, stream>>>(
        Wf2, Wf2T, DF_, DF_, 0, 0);
    cvt_h_kernel<<<(DD * DD) / 1024, blk, 0, stream>>>(Wq, Wqc, (long long)DD * DD);
    cvt_h_kernel<<<(DD * DD) / 1024, blk, 0, stream>>>(Wk, Wkc, (long long)DD * DD);
    cvt_h_kernel<<<(CC_ * DD) / 1024, blk, 0, stream>>>(
        basis, bas, (long long)CC_ * DD);
    zero_h_kernel<<<64, blk, 0, stream>>>(Wp1p, 131072);
    transpose_h_kernel<<<dim3(HH / 32, DD / 32, 1), blk, 0, stream>>>(
        Wp1, Wp1p, DD, HH, 0, 0);
    // pbias[i] = Wk[i,:] . bq ;  c2s[m] = s * (basis[m,:] . bq)
    rowdot_kernel<<<DD / 4, blk, 0, stream>>>(Wk, bq, pbias, 1.0f);
    rowdot_kernel<<<CC_ / 4, blk, 0, stream>>>(basis, bq, c2s, INV_SQRT_D);
    // P^T: P[e,i] = sum_o Wq[e,o] Wk[i,o]; OUT=2 -> packed(r=i, k=e)
    mfma_gemm<2><<<dim3(DD / 128, DD / 128, 1), blk, 0, stream>>>(
        Wqc, Wkc, nullptr, nullptr, Pt, DD, DD, DD, 0, 0, 0, 1.0f);
    // W2^T: W2[e,m] = sum_o Wq[e,o] bas[m,o]; OUT=2 -> packed(r=m, k=e)
    mfma_gemm<2><<<dim3(CC_ / 128, DD / 128, 1), blk, 0, stream>>>(
        Wqc, bas, nullptr, nullptr, W2t, DD, CC_, DD, 0, 0, 0, 1.0f);

    // ---- main pipeline ----
    // sensor = xT @ WembT^T + b_emb -> packed f16
    mfma_gemm<1><<<dim3(DD / 128, CC_ / 128, BB), blk, 0, stream>>>(
        xT, WembT, b_emb, nullptr, sens,
        CC_, DD, TT, (long long)CC_ * TT, 0, CD, 1.0f);
    layernorm_pr_kernel<<<(BB * CC_) / 32, blk, 0, stream>>>(sens, g_s, b_s);
    // QW = sens @ P + pbias -> packed (r=BC, K=D)   [= Q Wk^T exactly]
    mfma_gemm<1><<<dim3(DD / 128, (BB * CC_) / 128, 1), blk, 0, stream>>>(
        sens, Pt, pbias, nullptr, QWp,
        BB * CC_, DD, DD, 0, 0, 0, 1.0f);
    // S2T = (s*(sens @ W2) + s*c2)^T packed (rows m, K=C) per batch [= age_bias^T]
    mfma_gemm<2><<<dim3(CC_ / 128, CC_ / 128, BB), blk, 0, stream>>>(
        sens, W2t, c2s, nullptr, S2T,
        CC_, CC_, DD, CD, 0, CCs, INV_SQRT_D);
    // T1 = (s * QW @ sens^T)^T packed (rows k, K=C) per batch
    mfma_gemm<2><<<dim3(CC_ / 128, CC_ / 128, BB), blk, 0, stream>>>(
        QWp, sens, nullptr, nullptr, T1,
        CC_, CC_, DD, CD, CD, CCs, INV_SQRT_D);
    // S3[n,k] = sum_j S2T[n,j]*T1[k,j]   (fp32 out)
    mfma_gemm<0><<<dim3(CC_ / 128, CC_ / 128, BB), blk, 0, stream>>>(
        S2T, T1, nullptr, nullptr, S3,
        CC_, CC_, CC_, CCs, CCs, CCs, 1.0f);
    // attn = softmax(S3) -> packed fp16 (rows flat BC, K=C)
    softmax512_h_kernel<<<BB * CC_, blk, 0, stream>>>(S3, attn);
    // VT = (sensor @ Wv + bv)^T packed (rows D, K=C) per batch
    mfma_gemm<2><<<dim3(DD / 128, CC_ / 128, BB), blk, 0, stream>>>(
        sens, WvT, bv, nullptr, VT,
        CC_, DD, DD, CD, 0, DC, 1.0f);
    // fused = attn @ VT^T / 32 -> packed f16 (rows flat BC, K=D)
    mfma_gemm<1><<<dim3(DD / 128, CC_ / 128, BB), blk, 0, stream>>>(
        attn, VT, nullptr, nullptr, fusedp,
        CC_, DD, CC_, CCs, DC, CD, INV_SQRT_D);
    layernorm_pr_kernel<<<(BB * CC_) / 32, blk, 0, stream>>>(fusedp, g_f, b_f);
    // pool scores fused into the Wp1 GEMM (gelu + dot Wp2 + bp2 in epilogue)
    pool_fused_kernel<<<(BB * CC_) / 128, blk, 0, stream>>>(
        fusedp, Wp1p, bp1, Wp2, bp2, pscr, DD);
    softmax512_kernel<<<BB, blk, 0, stream>>>(pscr);
    // pooled (reads packed fused) -> packed f16
    pooled_kernel<<<dim3(DD / 256, BB), blk, 0, stream>>>(fusedp, pscr, pooledp);
    // fc head on MFMA:
    // h1 = leaky_relu(pooled @ Wf1 + bf1) -> packed (r=B, K=DF)
    mfma_gemm<1, 1><<<dim3(DF_ / 128, BB / 128, 1), blk, 0, stream>>>(
        pooledp, Wf1T, bf1, nullptr, h1p,
        BB, DF_, DD, 0, 0, 0, 1.0f);
    // h2 = h1 @ Wf2 + bf2  (fp32 out)
    mfma_gemm<0><<<dim3(DF_ / 128, BB / 128, 1), blk, 0, stream>>>(
        h1p, Wf2T, bf2, nullptr, h2,
        BB, DF_, DF_, 0, 0, 0, 1.0f);
    rul_kernel<<<BB, blk, 0, stream>>>(h2, Wf3, bf3, out);
}